// Round 2
// baseline (518.456 us; speedup 1.0000x reference)
//
#include <hip/hip_runtime.h>
#include <hip/hip_bf16.h>

// MHA: B=2, S=2048, E=2048, H=16, D=128. fp32 in/out, bf16 MFMA internally.
typedef __bf16 bf16;
typedef __bf16 bf16x8 __attribute__((ext_vector_type(8)));
typedef float f32x4 __attribute__((ext_vector_type(4)));

constexpr int kE = 2048;
constexpr int kS = 2048;
constexpr int kB = 2;
constexpr int kH = 16;
constexpr int kD = 128;
constexpr int kM = kB * kS;            // 4096 activation rows
constexpr float kQScale = 0.12751743f; // log2(e)/sqrt(D): softmax in exp2 domain

#define MFMA_BF16(A, B, C) __builtin_amdgcn_mfma_f32_16x16x32_bf16((A), (B), (C), 0, 0, 0)

// async global->LDS, 16B/lane. LDS dest must be WAVE-UNIFORM base; HW adds lane*16.
__device__ __forceinline__ void async_ld16(const void* gsrc, void* ldst) {
  __builtin_amdgcn_global_load_lds(
      (__attribute__((address_space(1))) void*)(gsrc),
      (__attribute__((address_space(3))) void*)(ldst), 16, 0, 0);
}

// ---------------------------------------------------------------------------
// Kernel 0: fp32 -> bf16 elementwise convert (query/key_in/value), 8 elem/lane.
__global__ __launch_bounds__(256) void cvt_kernel(
    const float* __restrict__ Xq, const float* __restrict__ Xk,
    const float* __restrict__ Xv, bf16* __restrict__ Y) {
  const int z = blockIdx.y;
  const float* X = (z == 0) ? Xq : (z == 1) ? Xk : Xv;
  bf16* Yz = Y + (size_t)z * kM * kE;
  size_t i = ((size_t)blockIdx.x * 256 + threadIdx.x) * 8;
  float4 v0 = *(const float4*)(X + i);
  float4 v1 = *(const float4*)(X + i + 4);
  bf16x8 hv;
  hv[0] = (bf16)v0.x; hv[1] = (bf16)v0.y; hv[2] = (bf16)v0.z; hv[3] = (bf16)v0.w;
  hv[4] = (bf16)v1.x; hv[5] = (bf16)v1.y; hv[6] = (bf16)v1.z; hv[7] = (bf16)v1.w;
  *(bf16x8*)(Yz + i) = hv;
}

// ---------------------------------------------------------------------------
// Kernel 1: W (E x E fp32, row-major K x N) -> W^T (N x K bf16), 4 matrices.
__global__ __launch_bounds__(256) void wt_kernel(
    const float* __restrict__ Wq, const float* __restrict__ Wk,
    const float* __restrict__ Wv, const float* __restrict__ Wo,
    bf16* __restrict__ WT) {
  __shared__ bf16 tl[64][72];  // [n][k]
  const int z = blockIdx.z;
  const float* W = (z == 0) ? Wq : (z == 1) ? Wk : (z == 2) ? Wv : Wo;
  const int n0 = blockIdx.x * 64, k0 = blockIdx.y * 64;
  const int t = threadIdx.x;

  {
    const int k = t >> 2, nq = (t & 3) * 16;
    const float* src = &W[(size_t)(k0 + k) * kE + n0 + nq];
#pragma unroll
    for (int u = 0; u < 4; ++u) {
      float4 v = *(const float4*)(src + u * 4);
      tl[nq + u * 4 + 0][k] = (bf16)v.x;
      tl[nq + u * 4 + 1][k] = (bf16)v.y;
      tl[nq + u * 4 + 2][k] = (bf16)v.z;
      tl[nq + u * 4 + 3][k] = (bf16)v.w;
    }
  }
  __syncthreads();
  {
    const int n = t >> 2, seg = (t & 3) * 16;
    bf16x8 a = *(const bf16x8*)&tl[n][seg];
    bf16x8 b2 = *(const bf16x8*)&tl[n][seg + 8];
    bf16* dst = &WT[(size_t)(z * kE + n0 + n) * kE + k0 + seg];
    *(bf16x8*)dst = a;
    *(bf16x8*)(dst + 8) = b2;
  }
}

// ---------------------------------------------------------------------------
// Kernel 2: QKV GEMM, 128x128 tile, 2-phase (proven 136.5 us combined).
// Parameterized per-z so the launcher splits into 3 dispatches of 512 blocks
// (2 exact CU rounds each) -> per-GEMM ~46 us, letting rocprof's top-5 expose
// the attention / output-projection kernels next round.
__global__ __launch_bounds__(256) void gemm_qkv_kernel(
    const bf16* __restrict__ A, const bf16* __restrict__ Bt,
    const float* __restrict__ bias, bf16* __restrict__ dstbuf,
    const float oscale) {
  __shared__ alignas(16) bf16 As[128 * 64];
  __shared__ alignas(16) bf16 Bs[128 * 64];

  const int n0 = blockIdx.x * 128;
  const int m0 = blockIdx.y * 128;
  const int t = threadIdx.x;
  const int lane = t & 63;
  const int w = t >> 6;
  const int ln = lane & 15;
  const int qd = lane >> 4;
  const int wm = w >> 1, wn = w & 1;

  const f32x4 fzero = {0.f, 0.f, 0.f, 0.f};
  f32x4 acc[4][4];
#pragma unroll
  for (int i = 0; i < 4; ++i)
#pragma unroll
    for (int j = 0; j < 4; ++j) acc[i][j] = fzero;

  for (int k0 = 0; k0 < kE; k0 += 64) {
    __syncthreads();
#pragma unroll
    for (int i = 0; i < 4; ++i) {
      int c = t + i * 256;
      int row = c >> 3;
      int slot = c & 7;
      int g = slot ^ (row & 7);
      async_ld16(&A[(size_t)(m0 + row) * kE + k0 + g * 8],
                 &As[(size_t)(w * 64 + i * 256) * 8]);
    }
#pragma unroll
    for (int i = 0; i < 4; ++i) {
      int c = t + i * 256;
      int row = c >> 3;
      int slot = c & 7;
      int g = slot ^ (row & 7);
      async_ld16(&Bt[(size_t)(n0 + row) * kE + k0 + g * 8],
                 &Bs[(size_t)(w * 64 + i * 256) * 8]);
    }
    __syncthreads();
#pragma unroll
    for (int ks = 0; ks < 2; ++ks) {
      bf16x8 af[4], bfv[4];
#pragma unroll
      for (int i = 0; i < 4; ++i) {
        int row = wm * 64 + i * 16 + ln;
        int slot = (ks * 4 + qd) ^ (ln & 7);
        af[i] = *(const bf16x8*)&As[row * 64 + slot * 8];
      }
#pragma unroll
      for (int j = 0; j < 4; ++j) {
        int row = wn * 64 + j * 16 + ln;
        int slot = (ks * 4 + qd) ^ (ln & 7);
        bfv[j] = *(const bf16x8*)&Bs[row * 64 + slot * 8];
      }
#pragma unroll
      for (int i = 0; i < 4; ++i)
#pragma unroll
        for (int j = 0; j < 4; ++j)
          acc[i][j] = MFMA_BF16(af[i], bfv[j], acc[i][j]);
    }
  }

  // epilogue: +bias, optional scale, coalesced (B,H,S,D) store.
#pragma unroll
  for (int i = 0; i < 4; ++i) {
    int mbase = m0 + wm * 64 + i * 16 + qd * 4;
#pragma unroll
    for (int j = 0; j < 4; ++j) {
      int n = n0 + wn * 64 + j * 16 + ln;
      float bn = bias[n];
      int h = n >> 7, d = n & 127;
#pragma unroll
      for (int r = 0; r < 4; ++r) {
        int mm = mbase + r;
        int bb = mm >> 11, ss = mm & (kS - 1);
        dstbuf[((size_t)(bb * kH + h) * kS + ss) * kD + d] =
            (bf16)((acc[i][j][r] + bn) * oscale);
      }
    }
  }
}

// ---------------------------------------------------------------------------
// Kernel 2b: V (B,H,S,D) -> V^T (B,H,D,S), 64x64 LDS transpose per (b,h).
__global__ __launch_bounds__(256) void vtrans_kernel(
    const bf16* __restrict__ Vb, bf16* __restrict__ VT) {
  __shared__ bf16 tl[64][72];  // [d][s]
  const int bh = blockIdx.z;
  const int s0 = blockIdx.x * 64, d0 = blockIdx.y * 64;
  const bf16* src = Vb + ((size_t)bh * kS + s0) * kD + d0;
  bf16* dst = VT + ((size_t)bh * kD + d0) * kS + s0;
  const int t = threadIdx.x;
#pragma unroll
  for (int i = 0; i < 2; ++i) {
    int c = t + i * 256;          // 512 chunks of 8
    int s = c >> 3, dc = (c & 7) * 8;
    bf16x8 v = *(const bf16x8*)&src[(size_t)s * kD + dc];
#pragma unroll
    for (int e = 0; e < 8; ++e) tl[dc + e][s] = v[e];
  }
  __syncthreads();
#pragma unroll
  for (int i = 0; i < 2; ++i) {
    int c = t + i * 256;
    int d = c >> 3, sc = (c & 7) * 8;
    bf16x8 v = *(const bf16x8*)&tl[d][sc];
    *(bf16x8*)&dst[(size_t)d * kS + sc] = v;
  }
}

// ---------------------------------------------------------------------------
// Kernel 3: flash attention. Round-2 change: QBLK 64 -> 128 (4 waves x 32
// q-rows each, 2 m-frags/wave). K/V fragments read once from LDS feed TWO
// MFMAs (m=0,1) -> LDS-read b128 count per 64 MFMA drops 34 -> 20, and K/V
// staging traffic per FLOP halves. All lane layouts / XOR swizzles identical
// to the verified QBLK=64 version; only an m*16 row offset is added on the
// Q-frag load, P write/read, and output rows.
__global__ __launch_bounds__(256) void attn_kernel(
    const bf16* __restrict__ Qb, const bf16* __restrict__ Kb,
    const bf16* __restrict__ VTb, bf16* __restrict__ AO) {
  __shared__ alignas(16) bf16 Kt[64 * 128];
  __shared__ alignas(16) bf16 Vt[128 * 64];
  __shared__ alignas(16) bf16 Pl[4][32 * 64];

  const int b = blockIdx.z, h = blockIdx.y;
  const int q0 = blockIdx.x * 128;
  const int t = threadIdx.x, lane = t & 63, w = t >> 6;
  const int ln = lane & 15, qd = lane >> 4;

  const bf16* Qh = Qb + (size_t)(b * kH + h) * kS * kD;
  const bf16* Kh = Kb + (size_t)(b * kH + h) * kS * kD;
  const bf16* Vh = VTb + (size_t)(b * kH + h) * kD * kS;

  bf16x8 qf[2][4];  // A-operand frags: m-frag, k = f*32+qd*8+j (d)
#pragma unroll
  for (int m = 0; m < 2; ++m) {
    int qr = q0 + w * 32 + m * 16 + ln;
#pragma unroll
    for (int f = 0; f < 4; ++f)
      qf[m][f] = *(const bf16x8*)&Qh[(size_t)qr * kD + f * 32 + qd * 8];
  }

  const f32x4 fzero = {0.f, 0.f, 0.f, 0.f};
  f32x4 o[2][8];
#pragma unroll
  for (int m = 0; m < 2; ++m)
#pragma unroll
    for (int dt = 0; dt < 8; ++dt) o[m][dt] = fzero;
  float lsum[2][4] = {{0.f, 0.f, 0.f, 0.f}, {0.f, 0.f, 0.f, 0.f}};

  for (int kc = 0; kc < kS; kc += 64) {
    __syncthreads();  // protect Kt/Vt from previous iteration's readers
#pragma unroll
    for (int i = 0; i < 4; ++i) {
      int c = t + i * 256;
      int row = c >> 4;
      int slot = c & 15;
      int g = slot ^ (row & 15);
      async_ld16(&Kh[(size_t)(kc + row) * kD + g * 8],
                 &Kt[(size_t)(w * 64 + i * 256) * 8]);
    }
#pragma unroll
    for (int i = 0; i < 4; ++i) {
      int c = t + i * 256;
      int row = c >> 3;
      int slot = c & 7;
      int g = slot ^ (row & 7);
      async_ld16(&Vh[(size_t)row * kS + kc + g * 8],
                 &Vt[(size_t)(w * 64 + i * 256) * 8]);
    }
    __syncthreads();

    // S = Q * K^T : per 16-tile, C row=query(qd*4+r), col=key(ln).
    // Each K fragment feeds both m-frags (the LDS-reuse lever).
    f32x4 s[2][4];
#pragma unroll
    for (int m = 0; m < 2; ++m)
#pragma unroll
      for (int nt = 0; nt < 4; ++nt) s[m][nt] = fzero;
#pragma unroll
    for (int nt = 0; nt < 4; ++nt) {
      int row = nt * 16 + ln;
#pragma unroll
      for (int f = 0; f < 4; ++f) {
        int slot = (f * 4 + qd) ^ ln;  // row&15 == ln
        bf16x8 kfv = *(const bf16x8*)&Kt[row * 128 + slot * 8];
        s[0][nt] = MFMA_BF16(qf[0][f], kfv, s[0][nt]);
        s[1][nt] = MFMA_BF16(qf[1][f], kfv, s[1][nt]);
      }
    }

    // P = exp2(S); accumulate per-lane partial row-sums; store P to LDS
#pragma unroll
    for (int m = 0; m < 2; ++m)
#pragma unroll
      for (int nt = 0; nt < 4; ++nt)
#pragma unroll
        for (int r = 0; r < 4; ++r) {
          float p = __builtin_amdgcn_exp2f(s[m][nt][r]);
          lsum[m][r] += p;
          int prow = m * 16 + qd * 4 + r;
          int gchunk = nt * 2 + (ln >> 3);
          int slot = gchunk ^ (prow & 7);
          Pl[w][prow * 64 + slot * 8 + (ln & 7)] = (bf16)p;
        }
    asm volatile("s_waitcnt lgkmcnt(0)" ::: "memory");  // per-wave P handoff

    // O += P * V : A = P (m=query, k=key), B = V (k=key, n=d).
    // Each V fragment feeds both m-frags.
    bf16x8 pf[2][2];
#pragma unroll
    for (int m = 0; m < 2; ++m)
#pragma unroll
      for (int kf = 0; kf < 2; ++kf) {
        int slot = (kf * 4 + qd) ^ (ln & 7);
        pf[m][kf] = *(const bf16x8*)&Pl[w][(m * 16 + ln) * 64 + slot * 8];
      }
#pragma unroll
    for (int dt = 0; dt < 8; ++dt) {
      int row = dt * 16 + ln;
#pragma unroll
      for (int kf = 0; kf < 2; ++kf) {
        int slot = (kf * 4 + qd) ^ (ln & 7);
        bf16x8 vv = *(const bf16x8*)&Vt[row * 64 + slot * 8];
        o[0][dt] = MFMA_BF16(pf[0][kf], vv, o[0][dt]);
        o[1][dt] = MFMA_BF16(pf[1][kf], vv, o[1][dt]);
      }
    }
  }

  // epilogue: reduce l across the 16-lane row group, normalize, write bf16
#pragma unroll
  for (int m = 0; m < 2; ++m)
#pragma unroll
    for (int r = 0; r < 4; ++r) {
      float l = lsum[m][r];
      l += __shfl_xor(l, 1);
      l += __shfl_xor(l, 2);
      l += __shfl_xor(l, 4);
      l += __shfl_xor(l, 8);
      float inv = 1.f / l;
      int srow = q0 + w * 32 + m * 16 + qd * 4 + r;
      bf16* dst = AO + (size_t)(b * kS + srow) * kE + h * kD;
#pragma unroll
      for (int dt = 0; dt < 8; ++dt)
        dst[dt * 16 + ln] = (bf16)(o[m][dt][r] * inv);
    }
}

// ---------------------------------------------------------------------------
// Kernel 4: output projection. A = attn out (bf16), out = fp32 d_out + bo.
__global__ __launch_bounds__(256) void gemm_out_kernel(
    const bf16* __restrict__ A, const bf16* __restrict__ Bt,
    const float* __restrict__ bias, float* __restrict__ out) {
  __shared__ alignas(16) bf16 As[128 * 64];
  __shared__ alignas(16) bf16 Bs[128 * 64];

  const int n0 = blockIdx.x * 128;
  const int m0 = blockIdx.y * 128;
  const int t = threadIdx.x;
  const int lane = t & 63;
  const int w = t >> 6;
  const int ln = lane & 15;
  const int qd = lane >> 4;
  const int wm = w >> 1, wn = w & 1;

  const f32x4 fzero = {0.f, 0.f, 0.f, 0.f};
  f32x4 acc[4][4];
#pragma unroll
  for (int i = 0; i < 4; ++i)
#pragma unroll
    for (int j = 0; j < 4; ++j) acc[i][j] = fzero;

  for (int k0 = 0; k0 < kE; k0 += 64) {
    __syncthreads();
#pragma unroll
    for (int i = 0; i < 4; ++i) {
      int c = t + i * 256;
      int row = c >> 3;
      int slot = c & 7;
      int g = slot ^ (row & 7);
      async_ld16(&A[(size_t)(m0 + row) * kE + k0 + g * 8],
                 &As[(size_t)(w * 64 + i * 256) * 8]);
    }
#pragma unroll
    for (int i = 0; i < 4; ++i) {
      int c = t + i * 256;
      int row = c >> 3;
      int slot = c & 7;
      int g = slot ^ (row & 7);
      async_ld16(&Bt[(size_t)(n0 + row) * kE + k0 + g * 8],
                 &Bs[(size_t)(w * 64 + i * 256) * 8]);
    }
    __syncthreads();
#pragma unroll
    for (int ks = 0; ks < 2; ++ks) {
      bf16x8 af[4], bfv[4];
#pragma unroll
      for (int i = 0; i < 4; ++i) {
        int row = wm * 64 + i * 16 + ln;
        int slot = (ks * 4 + qd) ^ (ln & 7);
        af[i] = *(const bf16x8*)&As[row * 64 + slot * 8];
      }
#pragma unroll
      for (int j = 0; j < 4; ++j) {
        int row = wn * 64 + j * 16 + ln;
        int slot = (ks * 4 + qd) ^ (ln & 7);
        bfv[j] = *(const bf16x8*)&Bs[row * 64 + slot * 8];
      }
#pragma unroll
      for (int i = 0; i < 4; ++i)
#pragma unroll
        for (int j = 0; j < 4; ++j)
          acc[i][j] = MFMA_BF16(af[i], bfv[j], acc[i][j]);
    }
  }

#pragma unroll
  for (int i = 0; i < 4; ++i) {
    int mbase = m0 + wm * 64 + i * 16 + qd * 4;
#pragma unroll
    for (int j = 0; j < 4; ++j) {
      int n = n0 + wn * 64 + j * 16 + ln;
      float bn = bias[n];
#pragma unroll
      for (int r = 0; r < 4; ++r) {
        int mm = mbase + r;
        out[(size_t)mm * kE + n] = acc[i][j][r] + bn;
      }
    }
  }
}

// ---------------------------------------------------------------------------
extern "C" void kernel_launch(void* const* d_in, const int* in_sizes, int n_in,
                              void* d_out, int out_size, void* d_ws,
                              size_t ws_size, hipStream_t stream) {
  const float* query  = (const float*)d_in[0];
  const float* key_in = (const float*)d_in[1];
  const float* value  = (const float*)d_in[2];
  const float* Wq = (const float*)d_in[3];
  const float* bq = (const float*)d_in[4];
  const float* Wk = (const float*)d_in[5];
  const float* bk = (const float*)d_in[6];
  const float* Wv = (const float*)d_in[7];
  const float* bv = (const float*)d_in[8];
  const float* Wo = (const float*)d_in[9];
  const float* bo = (const float*)d_in[10];
  float* out = (float*)d_out;

  // ws layout (bf16): WT[4*E*E] | Q | K | VT | AO (each kM*kE) | Xb[3*kM*kE]
  // V (B,H,S,D) staging aliases AO: vtrans consumes it before attn writes AO.
  const size_t szWT  = (size_t)4 * kE * kE;
  const size_t szAct = (size_t)kM * kE;
  const size_t need = (szWT + 7 * szAct) * sizeof(bf16);  // ~151 MB
  if (ws_size < need) return;

  bf16* WT  = (bf16*)d_ws;
  bf16* Qb  = WT + szWT;
  bf16* Kb  = Qb + szAct;
  bf16* VTb = Kb + szAct;
  bf16* AO  = VTb + szAct;
  bf16* Xb  = AO + szAct;
  bf16* Vb  = AO;  // alias: dead before attn, consumed by vtrans

  wt_kernel<<<dim3(kE / 64, kE / 64, 4), 256, 0, stream>>>(
      Wq, Wk, Wv, Wo, WT);
  cvt_kernel<<<dim3(kM * kE / 8 / 256, 3), 256, 0, stream>>>(
      query, key_in, value, Xb);
  // 3 separate z-dispatches (512 blocks = 2 exact CU rounds each): same total
  // work as the fused launch, but each sub-GEMM is ~46 us so rocprof's top-5
  // can expose the attention / projection kernels.
  gemm_qkv_kernel<<<dim3(kE / 128, kM / 128), 256, 0, stream>>>(
      Xb, WT, bq, Qb, kQScale);
  gemm_qkv_kernel<<<dim3(kE / 128, kM / 128), 256, 0, stream>>>(
      Xb + szAct, WT + (size_t)kE * kE, bk, Kb, 1.0f);
  gemm_qkv_kernel<<<dim3(kE / 128, kM / 128), 256, 0, stream>>>(
      Xb + 2 * szAct, WT + (size_t)2 * kE * kE, bv, Vb, 1.0f);
  vtrans_kernel<<<dim3(kS / 64, kD / 64, kB * kH), 256, 0, stream>>>(
      Vb, VTb);
  attn_kernel<<<dim3(kS / 128, kH, kB), 256, 0, stream>>>(Qb, Kb, VTb, AO);
  gemm_out_kernel<<<dim3(kE / 128, kM / 128), 256, 0, stream>>>(
      AO, WT + (size_t)3 * kE * kE, bo, out);
}

// Round 3
// 461.861 us; speedup vs baseline: 1.1225x; 1.1225x over previous
//
#include <hip/hip_runtime.h>
#include <hip/hip_bf16.h>

// MHA: B=2, S=2048, E=2048, H=16, D=128. fp32 in/out, bf16 MFMA internally.
typedef __bf16 bf16;
typedef __bf16 bf16x8 __attribute__((ext_vector_type(8)));
typedef float f32x4 __attribute__((ext_vector_type(4)));

constexpr int kE = 2048;
constexpr int kS = 2048;
constexpr int kB = 2;
constexpr int kH = 16;
constexpr int kD = 128;
constexpr int kM = kB * kS;            // 4096 activation rows
constexpr float kQScale = 0.12751743f; // log2(e)/sqrt(D): softmax in exp2 domain

#define MFMA_BF16(A, B, C) __builtin_amdgcn_mfma_f32_16x16x32_bf16((A), (B), (C), 0, 0, 0)

// async global->LDS, 16B/lane. LDS dest must be WAVE-UNIFORM base; HW adds lane*16.
__device__ __forceinline__ void async_ld16(const void* gsrc, void* ldst) {
  __builtin_amdgcn_global_load_lds(
      (__attribute__((address_space(1))) void*)(gsrc),
      (__attribute__((address_space(3))) void*)(ldst), 16, 0, 0);
}

// ---------------------------------------------------------------------------
// Kernel 0: fp32 -> bf16 elementwise convert (query/key_in/value), 8 elem/lane.
__global__ __launch_bounds__(256) void cvt_kernel(
    const float* __restrict__ Xq, const float* __restrict__ Xk,
    const float* __restrict__ Xv, bf16* __restrict__ Y) {
  const int z = blockIdx.y;
  const float* X = (z == 0) ? Xq : (z == 1) ? Xk : Xv;
  bf16* Yz = Y + (size_t)z * kM * kE;
  size_t i = ((size_t)blockIdx.x * 256 + threadIdx.x) * 8;
  float4 v0 = *(const float4*)(X + i);
  float4 v1 = *(const float4*)(X + i + 4);
  bf16x8 hv;
  hv[0] = (bf16)v0.x; hv[1] = (bf16)v0.y; hv[2] = (bf16)v0.z; hv[3] = (bf16)v0.w;
  hv[4] = (bf16)v1.x; hv[5] = (bf16)v1.y; hv[6] = (bf16)v1.z; hv[7] = (bf16)v1.w;
  *(bf16x8*)(Yz + i) = hv;
}

// ---------------------------------------------------------------------------
// Kernel 1: W (E x E fp32, row-major K x N) -> W^T (N x K bf16), 4 matrices.
__global__ __launch_bounds__(256) void wt_kernel(
    const float* __restrict__ Wq, const float* __restrict__ Wk,
    const float* __restrict__ Wv, const float* __restrict__ Wo,
    bf16* __restrict__ WT) {
  __shared__ bf16 tl[64][72];  // [n][k]
  const int z = blockIdx.z;
  const float* W = (z == 0) ? Wq : (z == 1) ? Wk : (z == 2) ? Wv : Wo;
  const int n0 = blockIdx.x * 64, k0 = blockIdx.y * 64;
  const int t = threadIdx.x;

  {
    const int k = t >> 2, nq = (t & 3) * 16;
    const float* src = &W[(size_t)(k0 + k) * kE + n0 + nq];
#pragma unroll
    for (int u = 0; u < 4; ++u) {
      float4 v = *(const float4*)(src + u * 4);
      tl[nq + u * 4 + 0][k] = (bf16)v.x;
      tl[nq + u * 4 + 1][k] = (bf16)v.y;
      tl[nq + u * 4 + 2][k] = (bf16)v.z;
      tl[nq + u * 4 + 3][k] = (bf16)v.w;
    }
  }
  __syncthreads();
  {
    const int n = t >> 2, seg = (t & 3) * 16;
    bf16x8 a = *(const bf16x8*)&tl[n][seg];
    bf16x8 b2 = *(const bf16x8*)&tl[n][seg + 8];
    bf16* dst = &WT[(size_t)(z * kE + n0 + n) * kE + k0 + seg];
    *(bf16x8*)dst = a;
    *(bf16x8*)(dst + 8) = b2;
  }
}

// ---------------------------------------------------------------------------
// Kernel 2: QKV GEMM, 128x128 tile, 2-phase (proven structure). One dispatch
// per z (512 blocks = 2 exact CU rounds each) for profiling clarity.
__global__ __launch_bounds__(256) void gemm_qkv_kernel(
    const bf16* __restrict__ A, const bf16* __restrict__ Bt,
    const float* __restrict__ bias, bf16* __restrict__ dstbuf,
    const float oscale) {
  __shared__ alignas(16) bf16 As[128 * 64];
  __shared__ alignas(16) bf16 Bs[128 * 64];

  const int n0 = blockIdx.x * 128;
  const int m0 = blockIdx.y * 128;
  const int t = threadIdx.x;
  const int lane = t & 63;
  const int w = t >> 6;
  const int ln = lane & 15;
  const int qd = lane >> 4;
  const int wm = w >> 1, wn = w & 1;

  const f32x4 fzero = {0.f, 0.f, 0.f, 0.f};
  f32x4 acc[4][4];
#pragma unroll
  for (int i = 0; i < 4; ++i)
#pragma unroll
    for (int j = 0; j < 4; ++j) acc[i][j] = fzero;

  for (int k0 = 0; k0 < kE; k0 += 64) {
    __syncthreads();
#pragma unroll
    for (int i = 0; i < 4; ++i) {
      int c = t + i * 256;
      int row = c >> 3;
      int slot = c & 7;
      int g = slot ^ (row & 7);
      async_ld16(&A[(size_t)(m0 + row) * kE + k0 + g * 8],
                 &As[(size_t)(w * 64 + i * 256) * 8]);
    }
#pragma unroll
    for (int i = 0; i < 4; ++i) {
      int c = t + i * 256;
      int row = c >> 3;
      int slot = c & 7;
      int g = slot ^ (row & 7);
      async_ld16(&Bt[(size_t)(n0 + row) * kE + k0 + g * 8],
                 &Bs[(size_t)(w * 64 + i * 256) * 8]);
    }
    __syncthreads();
#pragma unroll
    for (int ks = 0; ks < 2; ++ks) {
      bf16x8 af[4], bfv[4];
#pragma unroll
      for (int i = 0; i < 4; ++i) {
        int row = wm * 64 + i * 16 + ln;
        int slot = (ks * 4 + qd) ^ (ln & 7);
        af[i] = *(const bf16x8*)&As[row * 64 + slot * 8];
      }
#pragma unroll
      for (int j = 0; j < 4; ++j) {
        int row = wn * 64 + j * 16 + ln;
        int slot = (ks * 4 + qd) ^ (ln & 7);
        bfv[j] = *(const bf16x8*)&Bs[row * 64 + slot * 8];
      }
#pragma unroll
      for (int i = 0; i < 4; ++i)
#pragma unroll
        for (int j = 0; j < 4; ++j)
          acc[i][j] = MFMA_BF16(af[i], bfv[j], acc[i][j]);
    }
  }

  // epilogue: +bias, optional scale, coalesced (B,H,S,D) store.
#pragma unroll
  for (int i = 0; i < 4; ++i) {
    int mbase = m0 + wm * 64 + i * 16 + qd * 4;
#pragma unroll
    for (int j = 0; j < 4; ++j) {
      int n = n0 + wn * 64 + j * 16 + ln;
      float bn = bias[n];
      int h = n >> 7, d = n & 127;
#pragma unroll
      for (int r = 0; r < 4; ++r) {
        int mm = mbase + r;
        int bb = mm >> 11, ss = mm & (kS - 1);
        dstbuf[((size_t)(bb * kH + h) * kS + ss) * kD + d] =
            (bf16)((acc[i][j][r] + bn) * oscale);
      }
    }
  }
}

// ---------------------------------------------------------------------------
// Kernel 2b: V (B,H,S,D) -> V^T (B,H,D,S), 64x64 LDS transpose per (b,h).
__global__ __launch_bounds__(256) void vtrans_kernel(
    const bf16* __restrict__ Vb, bf16* __restrict__ VT) {
  __shared__ bf16 tl[64][72];  // [d][s]
  const int bh = blockIdx.z;
  const int s0 = blockIdx.x * 64, d0 = blockIdx.y * 64;
  const bf16* src = Vb + ((size_t)bh * kS + s0) * kD + d0;
  bf16* dst = VT + ((size_t)bh * kD + d0) * kS + s0;
  const int t = threadIdx.x;
#pragma unroll
  for (int i = 0; i < 2; ++i) {
    int c = t + i * 256;          // 512 chunks of 8
    int s = c >> 3, dc = (c & 7) * 8;
    bf16x8 v = *(const bf16x8*)&src[(size_t)s * kD + dc];
#pragma unroll
    for (int e = 0; e < 8; ++e) tl[dc + e][s] = v[e];
  }
  __syncthreads();
#pragma unroll
  for (int i = 0; i < 2; ++i) {
    int c = t + i * 256;
    int d = c >> 3, sc = (c & 7) * 8;
    bf16x8 v = *(const bf16x8*)&tl[d][sc];
    *(bf16x8*)&dst[(size_t)d * kS + sc] = v;
  }
}

// ---------------------------------------------------------------------------
// Kernel 3: flash attention, QBLK=128 (4 waves x 32 q-rows, 2 m-frags/wave).
// Round-3 changes (attacking the latency-bound signature: MfmaUtil 19%,
// VALUBusy 24%, occ 11%):
//  (a) 2-phase double-buffered K/V staging with counted vmcnt(8): next tile's
//      8 global_load_lds fly during current tile's compute; NO vmcnt(0) drain
//      in the loop (replaces __syncthreads, which drains everything).
//  (b) XCD-bijective block swizzle: each XCD owns 4 heads -> its K+V working
//      set = 4 MB = exactly its private L2 (fixes FETCH 139 MB vs 48 ideal).
//  (c) s_setprio(1) around MFMA clusters (T5, phase-split attn +4-7%).
__global__ __launch_bounds__(256) void attn_kernel(
    const bf16* __restrict__ Qb, const bf16* __restrict__ Kb,
    const bf16* __restrict__ VTb, bf16* __restrict__ AO) {
  __shared__ alignas(16) bf16 Kt[2][64 * 128];
  __shared__ alignas(16) bf16 Vt[2][128 * 64];
  __shared__ alignas(16) bf16 Pl[4][32 * 64];

  // 512 blocks; round-robin XCD assignment => wg&7 == XCD. Give each XCD a
  // contiguous swz-range = 4 heads (bh 4i..4i+3), all 16 q-blocks each.
  const int wg = blockIdx.x;
  const int swz = (wg & 7) * 64 + (wg >> 3);   // bijective, 512 % 8 == 0
  const int bh = swz >> 4;                     // 0..31  (= b*16 + h)
  const int q0 = (swz & 15) * 128;
  const int t = threadIdx.x, lane = t & 63, w = t >> 6;
  const int ln = lane & 15, qd = lane >> 4;

  const bf16* Qh = Qb + (size_t)bh * kS * kD;
  const bf16* Kh = Kb + (size_t)bh * kS * kD;
  const bf16* Vh = VTb + (size_t)bh * kD * kS;

  bf16x8 qf[2][4];  // A-operand frags: m-frag, k = f*32+qd*8+j (d)
#pragma unroll
  for (int m = 0; m < 2; ++m) {
    int qr = q0 + w * 32 + m * 16 + ln;
#pragma unroll
    for (int f = 0; f < 4; ++f)
      qf[m][f] = *(const bf16x8*)&Qh[(size_t)qr * kD + f * 32 + qd * 8];
  }

  // stage K/V tile kc..kc+63 into buffer `buf` (8 async loads / thread)
  auto stage = [&](int buf, int kc) {
#pragma unroll
    for (int i = 0; i < 4; ++i) {
      int c = t + i * 256;
      int row = c >> 4;
      int slot = c & 15;
      int g = slot ^ (row & 15);
      async_ld16(&Kh[(size_t)(kc + row) * kD + g * 8],
                 &Kt[buf][(size_t)(w * 64 + i * 256) * 8]);
    }
#pragma unroll
    for (int i = 0; i < 4; ++i) {
      int c = t + i * 256;
      int row = c >> 3;
      int slot = c & 7;
      int g = slot ^ (row & 7);
      async_ld16(&Vh[(size_t)row * kS + kc + g * 8],
                 &Vt[buf][(size_t)(w * 64 + i * 256) * 8]);
    }
  };

  const f32x4 fzero = {0.f, 0.f, 0.f, 0.f};
  f32x4 o[2][8];
#pragma unroll
  for (int m = 0; m < 2; ++m)
#pragma unroll
    for (int dt = 0; dt < 8; ++dt) o[m][dt] = fzero;
  float lsum[2][4] = {{0.f, 0.f, 0.f, 0.f}, {0.f, 0.f, 0.f, 0.f}};

  stage(0, 0);  // prologue

#pragma unroll 1
  for (int u = 0; u < 32; ++u) {
    const int cur = u & 1;
    // prefetch next tile (last iter re-stages tile 31 into the dead buffer)
    int knext = (u < 31) ? (u + 1) * 64 : 31 * 64;
    stage(cur ^ 1, knext);
    // wait: oldest 8 (current tile) landed; 8 (next tile) stay in flight
    asm volatile("s_waitcnt vmcnt(8)" ::: "memory");
    __builtin_amdgcn_s_barrier();
    asm volatile("" ::: "memory");

    // S = Q * K^T : per 16-tile, C row=query(qd*4+r), col=key(ln).
    f32x4 s[2][4];
#pragma unroll
    for (int m = 0; m < 2; ++m)
#pragma unroll
      for (int nt = 0; nt < 4; ++nt) s[m][nt] = fzero;
    __builtin_amdgcn_s_setprio(1);
#pragma unroll
    for (int nt = 0; nt < 4; ++nt) {
      int row = nt * 16 + ln;
#pragma unroll
      for (int f = 0; f < 4; ++f) {
        int slot = (f * 4 + qd) ^ ln;  // row&15 == ln
        bf16x8 kfv = *(const bf16x8*)&Kt[cur][row * 128 + slot * 8];
        s[0][nt] = MFMA_BF16(qf[0][f], kfv, s[0][nt]);
        s[1][nt] = MFMA_BF16(qf[1][f], kfv, s[1][nt]);
      }
    }
    __builtin_amdgcn_s_setprio(0);

    // P = exp2(S); accumulate per-lane partial row-sums; store P to LDS
#pragma unroll
    for (int m = 0; m < 2; ++m)
#pragma unroll
      for (int nt = 0; nt < 4; ++nt)
#pragma unroll
        for (int r = 0; r < 4; ++r) {
          float p = __builtin_amdgcn_exp2f(s[m][nt][r]);
          lsum[m][r] += p;
          int prow = m * 16 + qd * 4 + r;
          int gchunk = nt * 2 + (ln >> 3);
          int slot = gchunk ^ (prow & 7);
          Pl[w][prow * 64 + slot * 8 + (ln & 7)] = (bf16)p;
        }
    asm volatile("s_waitcnt lgkmcnt(0)" ::: "memory");  // per-wave P handoff

    // O += P * V : A = P (m=query, k=key), B = V (k=key, n=d).
    bf16x8 pf[2][2];
#pragma unroll
    for (int m = 0; m < 2; ++m)
#pragma unroll
      for (int kf = 0; kf < 2; ++kf) {
        int slot = (kf * 4 + qd) ^ (ln & 7);
        pf[m][kf] = *(const bf16x8*)&Pl[w][(m * 16 + ln) * 64 + slot * 8];
      }
    __builtin_amdgcn_s_setprio(1);
#pragma unroll
    for (int dt = 0; dt < 8; ++dt) {
      int row = dt * 16 + ln;
#pragma unroll
      for (int kf = 0; kf < 2; ++kf) {
        int slot = (kf * 4 + qd) ^ (ln & 7);
        bf16x8 vv = *(const bf16x8*)&Vt[cur][row * 64 + slot * 8];
        o[0][dt] = MFMA_BF16(pf[0][kf], vv, o[0][dt]);
        o[1][dt] = MFMA_BF16(pf[1][kf], vv, o[1][dt]);
      }
    }
    __builtin_amdgcn_s_setprio(0);

    // all waves done reading buf `cur` before next iter re-stages it
    asm volatile("s_waitcnt lgkmcnt(0)" ::: "memory");
    __builtin_amdgcn_s_barrier();
    asm volatile("" ::: "memory");
  }

  // epilogue: reduce l across the 16-lane row group, normalize, write bf16
#pragma unroll
  for (int m = 0; m < 2; ++m)
#pragma unroll
    for (int r = 0; r < 4; ++r) {
      float l = lsum[m][r];
      l += __shfl_xor(l, 1);
      l += __shfl_xor(l, 2);
      l += __shfl_xor(l, 4);
      l += __shfl_xor(l, 8);
      float inv = 1.f / l;
      int srow = q0 + w * 32 + m * 16 + qd * 4 + r;
      bf16* dst = AO + (size_t)((bh >> 4) * kS + srow) * kE + (bh & 15) * kD;
#pragma unroll
      for (int dt = 0; dt < 8; ++dt)
        dst[dt * 16 + ln] = (bf16)(o[m][dt][r] * inv);
    }
}

// ---------------------------------------------------------------------------
// Kernel 4: output projection. A = attn out (bf16), out = fp32 d_out + bo.
__global__ __launch_bounds__(256) void gemm_out_kernel(
    const bf16* __restrict__ A, const bf16* __restrict__ Bt,
    const float* __restrict__ bias, float* __restrict__ out) {
  __shared__ alignas(16) bf16 As[128 * 64];
  __shared__ alignas(16) bf16 Bs[128 * 64];

  const int n0 = blockIdx.x * 128;
  const int m0 = blockIdx.y * 128;
  const int t = threadIdx.x;
  const int lane = t & 63;
  const int w = t >> 6;
  const int ln = lane & 15;
  const int qd = lane >> 4;
  const int wm = w >> 1, wn = w & 1;

  const f32x4 fzero = {0.f, 0.f, 0.f, 0.f};
  f32x4 acc[4][4];
#pragma unroll
  for (int i = 0; i < 4; ++i)
#pragma unroll
    for (int j = 0; j < 4; ++j) acc[i][j] = fzero;

  for (int k0 = 0; k0 < kE; k0 += 64) {
    __syncthreads();
#pragma unroll
    for (int i = 0; i < 4; ++i) {
      int c = t + i * 256;
      int row = c >> 3;
      int slot = c & 7;
      int g = slot ^ (row & 7);
      async_ld16(&A[(size_t)(m0 + row) * kE + k0 + g * 8],
                 &As[(size_t)(w * 64 + i * 256) * 8]);
    }
#pragma unroll
    for (int i = 0; i < 4; ++i) {
      int c = t + i * 256;
      int row = c >> 3;
      int slot = c & 7;
      int g = slot ^ (row & 7);
      async_ld16(&Bt[(size_t)(n0 + row) * kE + k0 + g * 8],
                 &Bs[(size_t)(w * 64 + i * 256) * 8]);
    }
    __syncthreads();
#pragma unroll
    for (int ks = 0; ks < 2; ++ks) {
      bf16x8 af[4], bfv[4];
#pragma unroll
      for (int i = 0; i < 4; ++i) {
        int row = wm * 64 + i * 16 + ln;
        int slot = (ks * 4 + qd) ^ (ln & 7);
        af[i] = *(const bf16x8*)&As[row * 64 + slot * 8];
      }
#pragma unroll
      for (int j = 0; j < 4; ++j) {
        int row = wn * 64 + j * 16 + ln;
        int slot = (ks * 4 + qd) ^ (ln & 7);
        bfv[j] = *(const bf16x8*)&Bs[row * 64 + slot * 8];
      }
#pragma unroll
      for (int i = 0; i < 4; ++i)
#pragma unroll
        for (int j = 0; j < 4; ++j)
          acc[i][j] = MFMA_BF16(af[i], bfv[j], acc[i][j]);
    }
  }

#pragma unroll
  for (int i = 0; i < 4; ++i) {
    int mbase = m0 + wm * 64 + i * 16 + qd * 4;
#pragma unroll
    for (int j = 0; j < 4; ++j) {
      int n = n0 + wn * 64 + j * 16 + ln;
      float bn = bias[n];
#pragma unroll
      for (int r = 0; r < 4; ++r) {
        int mm = mbase + r;
        out[(size_t)mm * kE + n] = acc[i][j][r] + bn;
      }
    }
  }
}

// ---------------------------------------------------------------------------
extern "C" void kernel_launch(void* const* d_in, const int* in_sizes, int n_in,
                              void* d_out, int out_size, void* d_ws,
                              size_t ws_size, hipStream_t stream) {
  const float* query  = (const float*)d_in[0];
  const float* key_in = (const float*)d_in[1];
  const float* value  = (const float*)d_in[2];
  const float* Wq = (const float*)d_in[3];
  const float* bq = (const float*)d_in[4];
  const float* Wk = (const float*)d_in[5];
  const float* bk = (const float*)d_in[6];
  const float* Wv = (const float*)d_in[7];
  const float* bv = (const float*)d_in[8];
  const float* Wo = (const float*)d_in[9];
  const float* bo = (const float*)d_in[10];
  float* out = (float*)d_out;

  // ws layout (bf16): WT[4*E*E] | Q | K | VT | AO (each kM*kE) | Xb[3*kM*kE]
  // V (B,H,S,D) staging aliases AO: vtrans consumes it before attn writes AO.
  const size_t szWT  = (size_t)4 * kE * kE;
  const size_t szAct = (size_t)kM * kE;
  const size_t need = (szWT + 7 * szAct) * sizeof(bf16);  // ~151 MB
  if (ws_size < need) return;

  bf16* WT  = (bf16*)d_ws;
  bf16* Qb  = WT + szWT;
  bf16* Kb  = Qb + szAct;
  bf16* VTb = Kb + szAct;
  bf16* AO  = VTb + szAct;
  bf16* Xb  = AO + szAct;
  bf16* Vb  = AO;  // alias: dead before attn, consumed by vtrans

  wt_kernel<<<dim3(kE / 64, kE / 64, 4), 256, 0, stream>>>(
      Wq, Wk, Wv, Wo, WT);
  cvt_kernel<<<dim3(kM * kE / 8 / 256, 3), 256, 0, stream>>>(
      query, key_in, value, Xb);
  gemm_qkv_kernel<<<dim3(kE / 128, kM / 128), 256, 0, stream>>>(
      Xb, WT, bq, Qb, kQScale);
  gemm_qkv_kernel<<<dim3(kE / 128, kM / 128), 256, 0, stream>>>(
      Xb + szAct, WT + (size_t)kE * kE, bk, Kb, 1.0f);
  gemm_qkv_kernel<<<dim3(kE / 128, kM / 128), 256, 0, stream>>>(
      Xb + 2 * szAct, WT + (size_t)2 * kE * kE, bv, Vb, 1.0f);
  vtrans_kernel<<<dim3(kS / 64, kD / 64, kB * kH), 256, 0, stream>>>(
      Vb, VTb);
  attn_kernel<<<dim3(kS * kB * kH / 128), 256, 0, stream>>>(Qb, Kb, VTb, AO);
  gemm_out_kernel<<<dim3(kE / 128, kM / 128), 256, 0, stream>>>(
      AO, WT + (size_t)3 * kE * kE, bo, out);
}

// Round 4
// 438.944 us; speedup vs baseline: 1.1811x; 1.0522x over previous
//
#include <hip/hip_runtime.h>
#include <hip/hip_bf16.h>

// MHA: B=2, S=2048, E=2048, H=16, D=128. fp32 in/out, bf16 MFMA internally.
typedef __bf16 bf16;
typedef __bf16 bf16x4 __attribute__((ext_vector_type(4)));
typedef __bf16 bf16x8 __attribute__((ext_vector_type(8)));
typedef float f32x4 __attribute__((ext_vector_type(4)));

constexpr int kE = 2048;
constexpr int kS = 2048;
constexpr int kB = 2;
constexpr int kH = 16;
constexpr int kD = 128;
constexpr int kM = kB * kS;            // 4096 activation rows
constexpr float kQScale = 0.12751743f; // log2(e)/sqrt(D): softmax in exp2 domain

#define MFMA_BF16(A, B, C) __builtin_amdgcn_mfma_f32_16x16x32_bf16((A), (B), (C), 0, 0, 0)

// async global->LDS, 16B/lane. LDS dest must be WAVE-UNIFORM base; HW adds lane*16.
__device__ __forceinline__ void async_ld16(const void* gsrc, void* ldst) {
  __builtin_amdgcn_global_load_lds(
      (__attribute__((address_space(1))) void*)(gsrc),
      (__attribute__((address_space(3))) void*)(ldst), 16, 0, 0);
}

// ---------------------------------------------------------------------------
// Kernel 0 (fused prep): blocks [0,12288) = fp32->bf16 convert of q/k/v;
// blocks [12288,16384) = W -> W^T bf16 for the 4 weight matrices.
// The two jobs are independent; fusing removes one dispatch gap and lets the
// two memory-bound passes share the GPU.
__global__ __launch_bounds__(256) void prep_kernel(
    const float* __restrict__ Xq, const float* __restrict__ Xk,
    const float* __restrict__ Xv, bf16* __restrict__ Y,
    const float* __restrict__ Wq, const float* __restrict__ Wk,
    const float* __restrict__ Wv, const float* __restrict__ Wo,
    bf16* __restrict__ WT) {
  __shared__ bf16 tl[64][72];  // wt-branch only ([n][k], +8 pad)
  const int blk = blockIdx.x;
  const int t = threadIdx.x;

  if (blk < 12288) {
    // ---- cvt: 4096 blocks per z, 8 elem/lane
    const int z = blk >> 12;
    const int bx = blk & 4095;
    const float* X = (z == 0) ? Xq : (z == 1) ? Xk : Xv;
    bf16* Yz = Y + (size_t)z * kM * kE;
    size_t i = ((size_t)bx * 256 + t) * 8;
    float4 v0 = *(const float4*)(X + i);
    float4 v1 = *(const float4*)(X + i + 4);
    bf16x8 hv;
    hv[0] = (bf16)v0.x; hv[1] = (bf16)v0.y; hv[2] = (bf16)v0.z; hv[3] = (bf16)v0.w;
    hv[4] = (bf16)v1.x; hv[5] = (bf16)v1.y; hv[6] = (bf16)v1.z; hv[7] = (bf16)v1.w;
    *(bf16x8*)(Yz + i) = hv;
  } else {
    // ---- wt: 1024 blocks per matrix (32x32 tiles of 64x64)
    const int idx = blk - 12288;
    const int z = idx >> 10;
    const int xy = idx & 1023;
    const int n0 = (xy & 31) * 64, k0 = (xy >> 5) * 64;
    const float* W = (z == 0) ? Wq : (z == 1) ? Wk : (z == 2) ? Wv : Wo;
    {
      const int k = t >> 2, nq = (t & 3) * 16;
      const float* src = &W[(size_t)(k0 + k) * kE + n0 + nq];
#pragma unroll
      for (int u = 0; u < 4; ++u) {
        float4 v = *(const float4*)(src + u * 4);
        tl[nq + u * 4 + 0][k] = (bf16)v.x;
        tl[nq + u * 4 + 1][k] = (bf16)v.y;
        tl[nq + u * 4 + 2][k] = (bf16)v.z;
        tl[nq + u * 4 + 3][k] = (bf16)v.w;
      }
    }
    __syncthreads();
    {
      const int n = t >> 2, seg = (t & 3) * 16;
      bf16x8 a = *(const bf16x8*)&tl[n][seg];
      bf16x8 b2 = *(const bf16x8*)&tl[n][seg + 8];
      bf16* dst = &WT[(size_t)(z * kE + n0 + n) * kE + k0 + seg];
      *(bf16x8*)dst = a;
      *(bf16x8*)(dst + 8) = b2;
    }
  }
}

// ---------------------------------------------------------------------------
// Kernel 2: QKV GEMM, 128x128 tile, 2-phase (proven 136.5 us fused). Round-4
// change: z==2 (V) epilogue stores V^T (B,H,D,S) directly -- 4 r-consecutive
// accumulators (consecutive s for fixed d) pack into one 8B store. This kills
// the separate vtrans kernel. Within a block each (h,d) covers 128 consecutive
// s, so full 64B lines are written while L2-resident (no write amplification).
__global__ __launch_bounds__(256) void gemm_qkv_kernel(
    const bf16* __restrict__ Xb, const bf16* __restrict__ WT,
    const float* __restrict__ bq, const float* __restrict__ bk,
    const float* __restrict__ bv, bf16* __restrict__ Qb,
    bf16* __restrict__ Kb, bf16* __restrict__ VTb) {
  __shared__ alignas(16) bf16 As[128 * 64];
  __shared__ alignas(16) bf16 Bs[128 * 64];

  const int z = blockIdx.z;
  const bf16* A = Xb + (size_t)z * kM * kE;
  const float* bias = (z == 0) ? bq : (z == 1) ? bk : bv;
  const float oscale = (z == 0) ? kQScale : 1.0f;
  const bf16* Bt = WT + (size_t)z * kE * kE;

  const int n0 = blockIdx.x * 128;
  const int m0 = blockIdx.y * 128;
  const int t = threadIdx.x;
  const int lane = t & 63;
  const int w = t >> 6;
  const int ln = lane & 15;
  const int qd = lane >> 4;
  const int wm = w >> 1, wn = w & 1;

  const f32x4 fzero = {0.f, 0.f, 0.f, 0.f};
  f32x4 acc[4][4];
#pragma unroll
  for (int i = 0; i < 4; ++i)
#pragma unroll
    for (int j = 0; j < 4; ++j) acc[i][j] = fzero;

  for (int k0 = 0; k0 < kE; k0 += 64) {
    __syncthreads();
#pragma unroll
    for (int i = 0; i < 4; ++i) {
      int c = t + i * 256;
      int row = c >> 3;
      int slot = c & 7;
      int g = slot ^ (row & 7);
      async_ld16(&A[(size_t)(m0 + row) * kE + k0 + g * 8],
                 &As[(size_t)(w * 64 + i * 256) * 8]);
    }
#pragma unroll
    for (int i = 0; i < 4; ++i) {
      int c = t + i * 256;
      int row = c >> 3;
      int slot = c & 7;
      int g = slot ^ (row & 7);
      async_ld16(&Bt[(size_t)(n0 + row) * kE + k0 + g * 8],
                 &Bs[(size_t)(w * 64 + i * 256) * 8]);
    }
    __syncthreads();
#pragma unroll
    for (int ks = 0; ks < 2; ++ks) {
      bf16x8 af[4], bfv[4];
#pragma unroll
      for (int i = 0; i < 4; ++i) {
        int row = wm * 64 + i * 16 + ln;
        int slot = (ks * 4 + qd) ^ (ln & 7);
        af[i] = *(const bf16x8*)&As[row * 64 + slot * 8];
      }
#pragma unroll
      for (int j = 0; j < 4; ++j) {
        int row = wn * 64 + j * 16 + ln;
        int slot = (ks * 4 + qd) ^ (ln & 7);
        bfv[j] = *(const bf16x8*)&Bs[row * 64 + slot * 8];
      }
#pragma unroll
      for (int i = 0; i < 4; ++i)
#pragma unroll
        for (int j = 0; j < 4; ++j)
          acc[i][j] = MFMA_BF16(af[i], bfv[j], acc[i][j]);
    }
  }

  // epilogue: +bias (+scale for Q). Q/K: coalesced (B,H,S,D). V: direct V^T
  // (B,H,D,S) -- consecutive r = consecutive s for fixed d -> bf16x4 store.
  if (z != 2) {
    bf16* dstbuf = (z == 0) ? Qb : Kb;
#pragma unroll
    for (int i = 0; i < 4; ++i) {
      int mbase = m0 + wm * 64 + i * 16 + qd * 4;
#pragma unroll
      for (int j = 0; j < 4; ++j) {
        int n = n0 + wn * 64 + j * 16 + ln;
        float bn = bias[n];
        int h = n >> 7, d = n & 127;
#pragma unroll
        for (int r = 0; r < 4; ++r) {
          int mm = mbase + r;
          int bb = mm >> 11, ss = mm & (kS - 1);
          dstbuf[((size_t)(bb * kH + h) * kS + ss) * kD + d] =
              (bf16)((acc[i][j][r] + bn) * oscale);
        }
      }
    }
  } else {
#pragma unroll
    for (int i = 0; i < 4; ++i) {
      int mbase = m0 + wm * 64 + i * 16 + qd * 4;
      int bb = mbase >> 11, ss0 = mbase & (kS - 1);
#pragma unroll
      for (int j = 0; j < 4; ++j) {
        int n = n0 + wn * 64 + j * 16 + ln;
        float bn = bias[n];
        int h = n >> 7, d = n & 127;
        bf16x4 v;
#pragma unroll
        for (int r = 0; r < 4; ++r) v[r] = (bf16)(acc[i][j][r] + bn);
        *(bf16x4*)&VTb[((size_t)(bb * kH + h) * kD + d) * kS + ss0] = v;
      }
    }
  }
}

// ---------------------------------------------------------------------------
// Kernel 3: flash attention, QBLK=128 (4 waves x 32 q-rows, 2 m-frags/wave).
// 2-phase double-buffered K/V staging, counted vmcnt(8), XCD-bijective head
// clustering (each XCD owns 4 heads -> K/V L2-resident), setprio on MFMA.
// Measured 91 us, MfmaUtil 31%, FETCH 24.6 MB -- matched prediction; frozen.
__global__ __launch_bounds__(256) void attn_kernel(
    const bf16* __restrict__ Qb, const bf16* __restrict__ Kb,
    const bf16* __restrict__ VTb, bf16* __restrict__ AO) {
  __shared__ alignas(16) bf16 Kt[2][64 * 128];
  __shared__ alignas(16) bf16 Vt[2][128 * 64];
  __shared__ alignas(16) bf16 Pl[4][32 * 64];

  const int wg = blockIdx.x;
  const int swz = (wg & 7) * 64 + (wg >> 3);   // bijective, 512 % 8 == 0
  const int bh = swz >> 4;                     // 0..31  (= b*16 + h)
  const int q0 = (swz & 15) * 128;
  const int t = threadIdx.x, lane = t & 63, w = t >> 6;
  const int ln = lane & 15, qd = lane >> 4;

  const bf16* Qh = Qb + (size_t)bh * kS * kD;
  const bf16* Kh = Kb + (size_t)bh * kS * kD;
  const bf16* Vh = VTb + (size_t)bh * kD * kS;

  bf16x8 qf[2][4];  // A-operand frags: m-frag, k = f*32+qd*8+j (d)
#pragma unroll
  for (int m = 0; m < 2; ++m) {
    int qr = q0 + w * 32 + m * 16 + ln;
#pragma unroll
    for (int f = 0; f < 4; ++f)
      qf[m][f] = *(const bf16x8*)&Qh[(size_t)qr * kD + f * 32 + qd * 8];
  }

  auto stage = [&](int buf, int kc) {
#pragma unroll
    for (int i = 0; i < 4; ++i) {
      int c = t + i * 256;
      int row = c >> 4;
      int slot = c & 15;
      int g = slot ^ (row & 15);
      async_ld16(&Kh[(size_t)(kc + row) * kD + g * 8],
                 &Kt[buf][(size_t)(w * 64 + i * 256) * 8]);
    }
#pragma unroll
    for (int i = 0; i < 4; ++i) {
      int c = t + i * 256;
      int row = c >> 3;
      int slot = c & 7;
      int g = slot ^ (row & 7);
      async_ld16(&Vh[(size_t)row * kS + kc + g * 8],
                 &Vt[buf][(size_t)(w * 64 + i * 256) * 8]);
    }
  };

  const f32x4 fzero = {0.f, 0.f, 0.f, 0.f};
  f32x4 o[2][8];
#pragma unroll
  for (int m = 0; m < 2; ++m)
#pragma unroll
    for (int dt = 0; dt < 8; ++dt) o[m][dt] = fzero;
  float lsum[2][4] = {{0.f, 0.f, 0.f, 0.f}, {0.f, 0.f, 0.f, 0.f}};

  stage(0, 0);  // prologue

#pragma unroll 1
  for (int u = 0; u < 32; ++u) {
    const int cur = u & 1;
    int knext = (u < 31) ? (u + 1) * 64 : 31 * 64;
    stage(cur ^ 1, knext);
    asm volatile("s_waitcnt vmcnt(8)" ::: "memory");
    __builtin_amdgcn_s_barrier();
    asm volatile("" ::: "memory");

    // S = Q * K^T
    f32x4 s[2][4];
#pragma unroll
    for (int m = 0; m < 2; ++m)
#pragma unroll
      for (int nt = 0; nt < 4; ++nt) s[m][nt] = fzero;
    __builtin_amdgcn_s_setprio(1);
#pragma unroll
    for (int nt = 0; nt < 4; ++nt) {
      int row = nt * 16 + ln;
#pragma unroll
      for (int f = 0; f < 4; ++f) {
        int slot = (f * 4 + qd) ^ ln;  // row&15 == ln
        bf16x8 kfv = *(const bf16x8*)&Kt[cur][row * 128 + slot * 8];
        s[0][nt] = MFMA_BF16(qf[0][f], kfv, s[0][nt]);
        s[1][nt] = MFMA_BF16(qf[1][f], kfv, s[1][nt]);
      }
    }
    __builtin_amdgcn_s_setprio(0);

    // P = exp2(S); per-lane partial row-sums; P to LDS
#pragma unroll
    for (int m = 0; m < 2; ++m)
#pragma unroll
      for (int nt = 0; nt < 4; ++nt)
#pragma unroll
        for (int r = 0; r < 4; ++r) {
          float p = __builtin_amdgcn_exp2f(s[m][nt][r]);
          lsum[m][r] += p;
          int prow = m * 16 + qd * 4 + r;
          int gchunk = nt * 2 + (ln >> 3);
          int slot = gchunk ^ (prow & 7);
          Pl[w][prow * 64 + slot * 8 + (ln & 7)] = (bf16)p;
        }
    asm volatile("s_waitcnt lgkmcnt(0)" ::: "memory");  // per-wave P handoff

    // O += P * V
    bf16x8 pf[2][2];
#pragma unroll
    for (int m = 0; m < 2; ++m)
#pragma unroll
      for (int kf = 0; kf < 2; ++kf) {
        int slot = (kf * 4 + qd) ^ (ln & 7);
        pf[m][kf] = *(const bf16x8*)&Pl[w][(m * 16 + ln) * 64 + slot * 8];
      }
    __builtin_amdgcn_s_setprio(1);
#pragma unroll
    for (int dt = 0; dt < 8; ++dt) {
      int row = dt * 16 + ln;
#pragma unroll
      for (int kf = 0; kf < 2; ++kf) {
        int slot = (kf * 4 + qd) ^ (ln & 7);
        bf16x8 vv = *(const bf16x8*)&Vt[cur][row * 64 + slot * 8];
        o[0][dt] = MFMA_BF16(pf[0][kf], vv, o[0][dt]);
        o[1][dt] = MFMA_BF16(pf[1][kf], vv, o[1][dt]);
      }
    }
    __builtin_amdgcn_s_setprio(0);

    asm volatile("s_waitcnt lgkmcnt(0)" ::: "memory");
    __builtin_amdgcn_s_barrier();
    asm volatile("" ::: "memory");
  }

  // epilogue: reduce l across the 16-lane row group, normalize, write bf16
#pragma unroll
  for (int m = 0; m < 2; ++m)
#pragma unroll
    for (int r = 0; r < 4; ++r) {
      float l = lsum[m][r];
      l += __shfl_xor(l, 1);
      l += __shfl_xor(l, 2);
      l += __shfl_xor(l, 4);
      l += __shfl_xor(l, 8);
      float inv = 1.f / l;
      int srow = q0 + w * 32 + m * 16 + qd * 4 + r;
      bf16* dst = AO + (size_t)((bh >> 4) * kS + srow) * kE + (bh & 15) * kD;
#pragma unroll
      for (int dt = 0; dt < 8; ++dt)
        dst[dt * 16 + ln] = (bf16)(o[m][dt][r] * inv);
    }
}

// ---------------------------------------------------------------------------
// Kernel 4: output projection. A = attn out (bf16), out = fp32 d_out + bo.
__global__ __launch_bounds__(256) void gemm_out_kernel(
    const bf16* __restrict__ A, const bf16* __restrict__ Bt,
    const float* __restrict__ bias, float* __restrict__ out) {
  __shared__ alignas(16) bf16 As[128 * 64];
  __shared__ alignas(16) bf16 Bs[128 * 64];

  const int n0 = blockIdx.x * 128;
  const int m0 = blockIdx.y * 128;
  const int t = threadIdx.x;
  const int lane = t & 63;
  const int w = t >> 6;
  const int ln = lane & 15;
  const int qd = lane >> 4;
  const int wm = w >> 1, wn = w & 1;

  const f32x4 fzero = {0.f, 0.f, 0.f, 0.f};
  f32x4 acc[4][4];
#pragma unroll
  for (int i = 0; i < 4; ++i)
#pragma unroll
    for (int j = 0; j < 4; ++j) acc[i][j] = fzero;

  for (int k0 = 0; k0 < kE; k0 += 64) {
    __syncthreads();
#pragma unroll
    for (int i = 0; i < 4; ++i) {
      int c = t + i * 256;
      int row = c >> 3;
      int slot = c & 7;
      int g = slot ^ (row & 7);
      async_ld16(&A[(size_t)(m0 + row) * kE + k0 + g * 8],
                 &As[(size_t)(w * 64 + i * 256) * 8]);
    }
#pragma unroll
    for (int i = 0; i < 4; ++i) {
      int c = t + i * 256;
      int row = c >> 3;
      int slot = c & 7;
      int g = slot ^ (row & 7);
      async_ld16(&Bt[(size_t)(n0 + row) * kE + k0 + g * 8],
                 &Bs[(size_t)(w * 64 + i * 256) * 8]);
    }
    __syncthreads();
#pragma unroll
    for (int ks = 0; ks < 2; ++ks) {
      bf16x8 af[4], bfv[4];
#pragma unroll
      for (int i = 0; i < 4; ++i) {
        int row = wm * 64 + i * 16 + ln;
        int slot = (ks * 4 + qd) ^ (ln & 7);
        af[i] = *(const bf16x8*)&As[row * 64 + slot * 8];
      }
#pragma unroll
      for (int j = 0; j < 4; ++j) {
        int row = wn * 64 + j * 16 + ln;
        int slot = (ks * 4 + qd) ^ (ln & 7);
        bfv[j] = *(const bf16x8*)&Bs[row * 64 + slot * 8];
      }
#pragma unroll
      for (int i = 0; i < 4; ++i)
#pragma unroll
        for (int j = 0; j < 4; ++j)
          acc[i][j] = MFMA_BF16(af[i], bfv[j], acc[i][j]);
    }
  }

#pragma unroll
  for (int i = 0; i < 4; ++i) {
    int mbase = m0 + wm * 64 + i * 16 + qd * 4;
#pragma unroll
    for (int j = 0; j < 4; ++j) {
      int n = n0 + wn * 64 + j * 16 + ln;
      float bn = bias[n];
#pragma unroll
      for (int r = 0; r < 4; ++r) {
        int mm = mbase + r;
        out[(size_t)mm * kE + n] = acc[i][j][r] + bn;
      }
    }
  }
}

// ---------------------------------------------------------------------------
extern "C" void kernel_launch(void* const* d_in, const int* in_sizes, int n_in,
                              void* d_out, int out_size, void* d_ws,
                              size_t ws_size, hipStream_t stream) {
  const float* query  = (const float*)d_in[0];
  const float* key_in = (const float*)d_in[1];
  const float* value  = (const float*)d_in[2];
  const float* Wq = (const float*)d_in[3];
  const float* bq = (const float*)d_in[4];
  const float* Wk = (const float*)d_in[5];
  const float* bk = (const float*)d_in[6];
  const float* Wv = (const float*)d_in[7];
  const float* bv = (const float*)d_in[8];
  const float* Wo = (const float*)d_in[9];
  const float* bo = (const float*)d_in[10];
  float* out = (float*)d_out;

  // ws layout (bf16): WT[4*E*E] | Q | K | VT | AO (each kM*kE) | Xb[3*kM*kE]
  const size_t szWT  = (size_t)4 * kE * kE;
  const size_t szAct = (size_t)kM * kE;
  const size_t need = (szWT + 7 * szAct) * sizeof(bf16);  // ~151 MB
  if (ws_size < need) return;

  bf16* WT  = (bf16*)d_ws;
  bf16* Qb  = WT + szWT;
  bf16* Kb  = Qb + szAct;
  bf16* VTb = Kb + szAct;
  bf16* AO  = VTb + szAct;
  bf16* Xb  = AO + szAct;

  // 4 dispatches total (was 8): prep (cvt+wt), qkv (V^T fused), attn, out.
  prep_kernel<<<dim3(12288 + 4096), 256, 0, stream>>>(
      query, key_in, value, Xb, Wq, Wk, Wv, Wo, WT);
  gemm_qkv_kernel<<<dim3(kE / 128, kM / 128, 3), 256, 0, stream>>>(
      Xb, WT, bq, bk, bv, Qb, Kb, VTb);
  attn_kernel<<<dim3(kS * kB * kH / 128), 256, 0, stream>>>(Qb, Kb, VTb, AO);
  gemm_out_kernel<<<dim3(kE / 128, kM / 128), 256, 0, stream>>>(
      AO, WT + (size_t)3 * kE * kE, bo, out);
}

// Round 6
// 427.934 us; speedup vs baseline: 1.2115x; 1.0257x over previous
//
#include <hip/hip_runtime.h>
#include <hip/hip_bf16.h>

// MHA: B=2, S=2048, E=2048, H=16, D=128. fp32 in/out, bf16 MFMA internally.
typedef __bf16 bf16;
typedef __bf16 bf16x4 __attribute__((ext_vector_type(4)));
typedef __bf16 bf16x8 __attribute__((ext_vector_type(8)));
typedef float f32x4 __attribute__((ext_vector_type(4)));

constexpr int kE = 2048;
constexpr int kS = 2048;
constexpr int kB = 2;
constexpr int kH = 16;
constexpr int kD = 128;
constexpr int kM = kB * kS;            // 4096 activation rows
constexpr float kQScale = 0.12751743f; // log2(e)/sqrt(D): softmax in exp2 domain

#define MFMA_BF16(A, B, C) __builtin_amdgcn_mfma_f32_16x16x32_bf16((A), (B), (C), 0, 0, 0)

// async global->LDS, 16B/lane. LDS dest must be WAVE-UNIFORM base; HW adds lane*16.
__device__ __forceinline__ void async_ld16(const void* gsrc, void* ldst) {
  __builtin_amdgcn_global_load_lds(
      (__attribute__((address_space(1))) void*)(gsrc),
      (__attribute__((address_space(3))) void*)(ldst), 16, 0, 0);
}

// ---------------------------------------------------------------------------
// Kernel 0 (fused prep): blocks [0,12288) = fp32->bf16 convert of q/k/v;
// blocks [12288,16384) = W -> W^T bf16 for the 4 weight matrices.
__global__ __launch_bounds__(256) void prep_kernel(
    const float* __restrict__ Xq, const float* __restrict__ Xk,
    const float* __restrict__ Xv, bf16* __restrict__ Y,
    const float* __restrict__ Wq, const float* __restrict__ Wk,
    const float* __restrict__ Wv, const float* __restrict__ Wo,
    bf16* __restrict__ WT) {
  __shared__ bf16 tl[64][72];  // wt-branch only ([n][k], +8 pad)
  const int blk = blockIdx.x;
  const int t = threadIdx.x;

  if (blk < 12288) {
    // ---- cvt: 4096 blocks per z, 8 elem/lane
    const int z = blk >> 12;
    const int bx = blk & 4095;
    const float* X = (z == 0) ? Xq : (z == 1) ? Xk : Xv;
    bf16* Yz = Y + (size_t)z * kM * kE;
    size_t i = ((size_t)bx * 256 + t) * 8;
    float4 v0 = *(const float4*)(X + i);
    float4 v1 = *(const float4*)(X + i + 4);
    bf16x8 hv;
    hv[0] = (bf16)v0.x; hv[1] = (bf16)v0.y; hv[2] = (bf16)v0.z; hv[3] = (bf16)v0.w;
    hv[4] = (bf16)v1.x; hv[5] = (bf16)v1.y; hv[6] = (bf16)v1.z; hv[7] = (bf16)v1.w;
    *(bf16x8*)(Yz + i) = hv;
  } else {
    // ---- wt: 1024 blocks per matrix (32x32 tiles of 64x64)
    const int idx = blk - 12288;
    const int z = idx >> 10;
    const int xy = idx & 1023;
    const int n0 = (xy & 31) * 64, k0 = (xy >> 5) * 64;
    const float* W = (z == 0) ? Wq : (z == 1) ? Wk : (z == 2) ? Wv : Wo;
    {
      const int k = t >> 2, nq = (t & 3) * 16;
      const float* src = &W[(size_t)(k0 + k) * kE + n0 + nq];
#pragma unroll
      for (int u = 0; u < 4; ++u) {
        float4 v = *(const float4*)(src + u * 4);
        tl[nq + u * 4 + 0][k] = (bf16)v.x;
        tl[nq + u * 4 + 1][k] = (bf16)v.y;
        tl[nq + u * 4 + 2][k] = (bf16)v.z;
        tl[nq + u * 4 + 3][k] = (bf16)v.w;
      }
    }
    __syncthreads();
    {
      const int n = t >> 2, seg = (t & 3) * 16;
      bf16x8 a = *(const bf16x8*)&tl[n][seg];
      bf16x8 b2 = *(const bf16x8*)&tl[n][seg + 8];
      bf16* dst = &WT[(size_t)(z * kE + n0 + n) * kE + k0 + seg];
      *(bf16x8*)dst = a;
      *(bf16x8*)(dst + 8) = b2;
    }
  }
}

// ---------------------------------------------------------------------------
// Kernel 2: QKV GEMM, 128x128 tile. Round-5 change: the attn-proven 2-phase
// double-buffer transformation (152->91 us on attn with this exact skeleton):
// stage NEXT k-tile before computing current; counted vmcnt(8) instead of the
// __syncthreads full drain; raw s_barrier + trailing lgkmcnt(0)+s_barrier.
// Stage/fragment-read/MFMA/epilogue code is byte-identical to the proven
// version; only the sync/buffering skeleton changes. LDS 32->64 KB (2 blk/CU,
// same as measured occupancy today).
__global__ __launch_bounds__(256) void gemm_qkv_kernel(
    const bf16* __restrict__ Xb, const bf16* __restrict__ WT,
    const float* __restrict__ bq, const float* __restrict__ bk,
    const float* __restrict__ bv, bf16* __restrict__ Qb,
    bf16* __restrict__ Kb, bf16* __restrict__ VTb) {
  __shared__ alignas(16) bf16 As[2][128 * 64];
  __shared__ alignas(16) bf16 Bs[2][128 * 64];

  const int z = blockIdx.z;
  const bf16* A = Xb + (size_t)z * kM * kE;
  const float* bias = (z == 0) ? bq : (z == 1) ? bk : bv;
  const float oscale = (z == 0) ? kQScale : 1.0f;
  const bf16* Bt = WT + (size_t)z * kE * kE;

  const int n0 = blockIdx.x * 128;
  const int m0 = blockIdx.y * 128;
  const int t = threadIdx.x;
  const int lane = t & 63;
  const int w = t >> 6;
  const int ln = lane & 15;
  const int qd = lane >> 4;
  const int wm = w >> 1, wn = w & 1;

  // stage one 64-wide k-slice of A and B (8 async loads / thread)
  auto stageAB = [&](int buf, int k0) {
#pragma unroll
    for (int i = 0; i < 4; ++i) {
      int c = t + i * 256;
      int row = c >> 3;
      int slot = c & 7;
      int g = slot ^ (row & 7);
      async_ld16(&A[(size_t)(m0 + row) * kE + k0 + g * 8],
                 &As[buf][(size_t)(w * 64 + i * 256) * 8]);
    }
#pragma unroll
    for (int i = 0; i < 4; ++i) {
      int c = t + i * 256;
      int row = c >> 3;
      int slot = c & 7;
      int g = slot ^ (row & 7);
      async_ld16(&Bt[(size_t)(n0 + row) * kE + k0 + g * 8],
                 &Bs[buf][(size_t)(w * 64 + i * 256) * 8]);
    }
  };

  const f32x4 fzero = {0.f, 0.f, 0.f, 0.f};
  f32x4 acc[4][4];
#pragma unroll
  for (int i = 0; i < 4; ++i)
#pragma unroll
    for (int j = 0; j < 4; ++j) acc[i][j] = fzero;

  stageAB(0, 0);  // prologue

#pragma unroll 1
  for (int u = 0; u < 32; ++u) {
    const int cur = u & 1;
    int kn = (u < 31) ? (u + 1) * 64 : 31 * 64;  // last iter: dead re-stage
    stageAB(cur ^ 1, kn);
    // oldest 8 (current tile) landed; 8 (next tile) stay in flight
    asm volatile("s_waitcnt vmcnt(8)" ::: "memory");
    __builtin_amdgcn_s_barrier();
    asm volatile("" ::: "memory");

    __builtin_amdgcn_s_setprio(1);
#pragma unroll
    for (int ks = 0; ks < 2; ++ks) {
      bf16x8 af[4], bfv[4];
#pragma unroll
      for (int i = 0; i < 4; ++i) {
        int row = wm * 64 + i * 16 + ln;
        int slot = (ks * 4 + qd) ^ (ln & 7);
        af[i] = *(const bf16x8*)&As[cur][row * 64 + slot * 8];
      }
#pragma unroll
      for (int j = 0; j < 4; ++j) {
        int row = wn * 64 + j * 16 + ln;
        int slot = (ks * 4 + qd) ^ (ln & 7);
        bfv[j] = *(const bf16x8*)&Bs[cur][row * 64 + slot * 8];
      }
#pragma unroll
      for (int i = 0; i < 4; ++i)
#pragma unroll
        for (int j = 0; j < 4; ++j)
          acc[i][j] = MFMA_BF16(af[i], bfv[j], acc[i][j]);
    }
    __builtin_amdgcn_s_setprio(0);

    // all waves done reading buf `cur` before next iter re-stages it
    asm volatile("s_waitcnt lgkmcnt(0)" ::: "memory");
    __builtin_amdgcn_s_barrier();
    asm volatile("" ::: "memory");
  }

  // epilogue: +bias (+scale for Q). Q/K: coalesced (B,H,S,D). V: direct V^T
  // (B,H,D,S) -- consecutive r = consecutive s for fixed d -> bf16x4 store.
  if (z != 2) {
    bf16* dstbuf = (z == 0) ? Qb : Kb;
#pragma unroll
    for (int i = 0; i < 4; ++i) {
      int mbase = m0 + wm * 64 + i * 16 + qd * 4;
#pragma unroll
      for (int j = 0; j < 4; ++j) {
        int n = n0 + wn * 64 + j * 16 + ln;
        float bn = bias[n];
        int h = n >> 7, d = n & 127;
#pragma unroll
        for (int r = 0; r < 4; ++r) {
          int mm = mbase + r;
          int bb = mm >> 11, ss = mm & (kS - 1);
          dstbuf[((size_t)(bb * kH + h) * kS + ss) * kD + d] =
              (bf16)((acc[i][j][r] + bn) * oscale);
        }
      }
    }
  } else {
#pragma unroll
    for (int i = 0; i < 4; ++i) {
      int mbase = m0 + wm * 64 + i * 16 + qd * 4;
      int bb = mbase >> 11, ss0 = mbase & (kS - 1);
#pragma unroll
      for (int j = 0; j < 4; ++j) {
        int n = n0 + wn * 64 + j * 16 + ln;
        float bn = bias[n];
        int h = n >> 7, d = n & 127;
        bf16x4 v;
#pragma unroll
        for (int r = 0; r < 4; ++r) v[r] = (bf16)(acc[i][j][r] + bn);
        *(bf16x4*)&VTb[((size_t)(bb * kH + h) * kD + d) * kS + ss0] = v;
      }
    }
  }
}

// ---------------------------------------------------------------------------
// Kernel 3: flash attention, QBLK=128 (4 waves x 32 q-rows, 2 m-frags/wave).
// 2-phase double-buffered K/V staging, counted vmcnt(8), XCD-bijective head
// clustering, setprio on MFMA. Measured 91 us, MfmaUtil 31%; frozen.
__global__ __launch_bounds__(256) void attn_kernel(
    const bf16* __restrict__ Qb, const bf16* __restrict__ Kb,
    const bf16* __restrict__ VTb, bf16* __restrict__ AO) {
  __shared__ alignas(16) bf16 Kt[2][64 * 128];
  __shared__ alignas(16) bf16 Vt[2][128 * 64];
  __shared__ alignas(16) bf16 Pl[4][32 * 64];

  const int wg = blockIdx.x;
  const int swz = (wg & 7) * 64 + (wg >> 3);   // bijective, 512 % 8 == 0
  const int bh = swz >> 4;                     // 0..31  (= b*16 + h)
  const int q0 = (swz & 15) * 128;
  const int t = threadIdx.x, lane = t & 63, w = t >> 6;
  const int ln = lane & 15, qd = lane >> 4;

  const bf16* Qh = Qb + (size_t)bh * kS * kD;
  const bf16* Kh = Kb + (size_t)bh * kS * kD;
  const bf16* Vh = VTb + (size_t)bh * kD * kS;

  bf16x8 qf[2][4];  // A-operand frags: m-frag, k = f*32+qd*8+j (d)
#pragma unroll
  for (int m = 0; m < 2; ++m) {
    int qr = q0 + w * 32 + m * 16 + ln;
#pragma unroll
    for (int f = 0; f < 4; ++f)
      qf[m][f] = *(const bf16x8*)&Qh[(size_t)qr * kD + f * 32 + qd * 8];
  }

  auto stage = [&](int buf, int kc) {
#pragma unroll
    for (int i = 0; i < 4; ++i) {
      int c = t + i * 256;
      int row = c >> 4;
      int slot = c & 15;
      int g = slot ^ (row & 15);
      async_ld16(&Kh[(size_t)(kc + row) * kD + g * 8],
                 &Kt[buf][(size_t)(w * 64 + i * 256) * 8]);
    }
#pragma unroll
    for (int i = 0; i < 4; ++i) {
      int c = t + i * 256;
      int row = c >> 3;
      int slot = c & 7;
      int g = slot ^ (row & 7);
      async_ld16(&Vh[(size_t)row * kS + kc + g * 8],
                 &Vt[buf][(size_t)(w * 64 + i * 256) * 8]);
    }
  };

  const f32x4 fzero = {0.f, 0.f, 0.f, 0.f};
  f32x4 o[2][8];
#pragma unroll
  for (int m = 0; m < 2; ++m)
#pragma unroll
    for (int dt = 0; dt < 8; ++dt) o[m][dt] = fzero;
  float lsum[2][4] = {{0.f, 0.f, 0.f, 0.f}, {0.f, 0.f, 0.f, 0.f}};

  stage(0, 0);  // prologue

#pragma unroll 1
  for (int u = 0; u < 32; ++u) {
    const int cur = u & 1;
    int knext = (u < 31) ? (u + 1) * 64 : 31 * 64;
    stage(cur ^ 1, knext);
    asm volatile("s_waitcnt vmcnt(8)" ::: "memory");
    __builtin_amdgcn_s_barrier();
    asm volatile("" ::: "memory");

    // S = Q * K^T
    f32x4 s[2][4];
#pragma unroll
    for (int m = 0; m < 2; ++m)
#pragma unroll
      for (int nt = 0; nt < 4; ++nt) s[m][nt] = fzero;
    __builtin_amdgcn_s_setprio(1);
#pragma unroll
    for (int nt = 0; nt < 4; ++nt) {
      int row = nt * 16 + ln;
#pragma unroll
      for (int f = 0; f < 4; ++f) {
        int slot = (f * 4 + qd) ^ ln;  // row&15 == ln
        bf16x8 kfv = *(const bf16x8*)&Kt[cur][row * 128 + slot * 8];
        s[0][nt] = MFMA_BF16(qf[0][f], kfv, s[0][nt]);
        s[1][nt] = MFMA_BF16(qf[1][f], kfv, s[1][nt]);
      }
    }
    __builtin_amdgcn_s_setprio(0);

    // P = exp2(S); per-lane partial row-sums; P to LDS
#pragma unroll
    for (int m = 0; m < 2; ++m)
#pragma unroll
      for (int nt = 0; nt < 4; ++nt)
#pragma unroll
        for (int r = 0; r < 4; ++r) {
          float p = __builtin_amdgcn_exp2f(s[m][nt][r]);
          lsum[m][r] += p;
          int prow = m * 16 + qd * 4 + r;
          int gchunk = nt * 2 + (ln >> 3);
          int slot = gchunk ^ (prow & 7);
          Pl[w][prow * 64 + slot * 8 + (ln & 7)] = (bf16)p;
        }
    asm volatile("s_waitcnt lgkmcnt(0)" ::: "memory");  // per-wave P handoff

    // O += P * V
    bf16x8 pf[2][2];
#pragma unroll
    for (int m = 0; m < 2; ++m)
#pragma unroll
      for (int kf = 0; kf < 2; ++kf) {
        int slot = (kf * 4 + qd) ^ (ln & 7);
        pf[m][kf] = *(const bf16x8*)&Pl[w][(m * 16 + ln) * 64 + slot * 8];
      }
    __builtin_amdgcn_s_setprio(1);
#pragma unroll
    for (int dt = 0; dt < 8; ++dt) {
      int row = dt * 16 + ln;
#pragma unroll
      for (int kf = 0; kf < 2; ++kf) {
        int slot = (kf * 4 + qd) ^ (ln & 7);
        bf16x8 vv = *(const bf16x8*)&Vt[cur][row * 64 + slot * 8];
        o[0][dt] = MFMA_BF16(pf[0][kf], vv, o[0][dt]);
        o[1][dt] = MFMA_BF16(pf[1][kf], vv, o[1][dt]);
      }
    }
    __builtin_amdgcn_s_setprio(0);

    asm volatile("s_waitcnt lgkmcnt(0)" ::: "memory");
    __builtin_amdgcn_s_barrier();
    asm volatile("" ::: "memory");
  }

  // epilogue: reduce l across the 16-lane row group, normalize, write bf16
#pragma unroll
  for (int m = 0; m < 2; ++m)
#pragma unroll
    for (int r = 0; r < 4; ++r) {
      float l = lsum[m][r];
      l += __shfl_xor(l, 1);
      l += __shfl_xor(l, 2);
      l += __shfl_xor(l, 4);
      l += __shfl_xor(l, 8);
      float inv = 1.f / l;
      int srow = q0 + w * 32 + m * 16 + qd * 4 + r;
      bf16* dst = AO + (size_t)((bh >> 4) * kS + srow) * kE + (bh & 15) * kD;
#pragma unroll
      for (int dt = 0; dt < 8; ++dt)
        dst[dt * 16 + ln] = (bf16)(o[m][dt][r] * inv);
    }
}

// ---------------------------------------------------------------------------
// Kernel 4: output projection, same 2-phase dbuf skeleton as gemm_qkv.
__global__ __launch_bounds__(256) void gemm_out_kernel(
    const bf16* __restrict__ A, const bf16* __restrict__ Bt,
    const float* __restrict__ bias, float* __restrict__ out) {
  __shared__ alignas(16) bf16 As[2][128 * 64];
  __shared__ alignas(16) bf16 Bs[2][128 * 64];

  const int n0 = blockIdx.x * 128;
  const int m0 = blockIdx.y * 128;
  const int t = threadIdx.x;
  const int lane = t & 63;
  const int w = t >> 6;
  const int ln = lane & 15;
  const int qd = lane >> 4;
  const int wm = w >> 1, wn = w & 1;

  auto stageAB = [&](int buf, int k0) {
#pragma unroll
    for (int i = 0; i < 4; ++i) {
      int c = t + i * 256;
      int row = c >> 3;
      int slot = c & 7;
      int g = slot ^ (row & 7);
      async_ld16(&A[(size_t)(m0 + row) * kE + k0 + g * 8],
                 &As[buf][(size_t)(w * 64 + i * 256) * 8]);
    }
#pragma unroll
    for (int i = 0; i < 4; ++i) {
      int c = t + i * 256;
      int row = c >> 3;
      int slot = c & 7;
      int g = slot ^ (row & 7);
      async_ld16(&Bt[(size_t)(n0 + row) * kE + k0 + g * 8],
                 &Bs[buf][(size_t)(w * 64 + i * 256) * 8]);
    }
  };

  const f32x4 fzero = {0.f, 0.f, 0.f, 0.f};
  f32x4 acc[4][4];
#pragma unroll
  for (int i = 0; i < 4; ++i)
#pragma unroll
    for (int j = 0; j < 4; ++j) acc[i][j] = fzero;

  stageAB(0, 0);  // prologue

#pragma unroll 1
  for (int u = 0; u < 32; ++u) {
    const int cur = u & 1;
    int kn = (u < 31) ? (u + 1) * 64 : 31 * 64;
    stageAB(cur ^ 1, kn);
    asm volatile("s_waitcnt vmcnt(8)" ::: "memory");
    __builtin_amdgcn_s_barrier();
    asm volatile("" ::: "memory");

    __builtin_amdgcn_s_setprio(1);
#pragma unroll
    for (int ks = 0; ks < 2; ++ks) {
      bf16x8 af[4], bfv[4];
#pragma unroll
      for (int i = 0; i < 4; ++i) {
        int row = wm * 64 + i * 16 + ln;
        int slot = (ks * 4 + qd) ^ (ln & 7);
        af[i] = *(const bf16x8*)&As[cur][row * 64 + slot * 8];
      }
#pragma unroll
      for (int j = 0; j < 4; ++j) {
        int row = wn * 64 + j * 16 + ln;
        int slot = (ks * 4 + qd) ^ (ln & 7);
        bfv[j] = *(const bf16x8*)&Bs[cur][row * 64 + slot * 8];
      }
#pragma unroll
      for (int i = 0; i < 4; ++i)
#pragma unroll
        for (int j = 0; j < 4; ++j)
          acc[i][j] = MFMA_BF16(af[i], bfv[j], acc[i][j]);
    }
    __builtin_amdgcn_s_setprio(0);

    asm volatile("s_waitcnt lgkmcnt(0)" ::: "memory");
    __builtin_amdgcn_s_barrier();
    asm volatile("" ::: "memory");
  }

#pragma unroll
  for (int i = 0; i < 4; ++i) {
    int mbase = m0 + wm * 64 + i * 16 + qd * 4;
#pragma unroll
    for (int j = 0; j < 4; ++j) {
      int n = n0 + wn * 64 + j * 16 + ln;
      float bn = bias[n];
#pragma unroll
      for (int r = 0; r < 4; ++r) {
        int mm = mbase + r;
        out[(size_t)mm * kE + n] = acc[i][j][r] + bn;
      }
    }
  }
}

// ---------------------------------------------------------------------------
extern "C" void kernel_launch(void* const* d_in, const int* in_sizes, int n_in,
                              void* d_out, int out_size, void* d_ws,
                              size_t ws_size, hipStream_t stream) {
  const float* query  = (const float*)d_in[0];
  const float* key_in = (const float*)d_in[1];
  const float* value  = (const float*)d_in[2];
  const float* Wq = (const float*)d_in[3];
  const float* bq = (const float*)d_in[4];
  const float* Wk = (const float*)d_in[5];
  const float* bk = (const float*)d_in[6];
  const float* Wv = (const float*)d_in[7];
  const float* bv = (const float*)d_in[8];
  const float* Wo = (const float*)d_in[9];
  const float* bo = (const float*)d_in[10];
  float* out = (float*)d_out;

  // ws layout (bf16): WT[4*E*E] | Q | K | VT | AO (each kM*kE) | Xb[3*kM*kE]
  const size_t szWT  = (size_t)4 * kE * kE;
  const size_t szAct = (size_t)kM * kE;
  const size_t need = (szWT + 7 * szAct) * sizeof(bf16);  // ~151 MB
  if (ws_size < need) return;

  bf16* WT  = (bf16*)d_ws;
  bf16* Qb  = WT + szWT;
  bf16* Kb  = Qb + szAct;
  bf16* VTb = Kb + szAct;
  bf16* AO  = VTb + szAct;
  bf16* Xb  = AO + szAct;

  // 4 dispatches: prep (cvt+wt), qkv (V^T fused), attn, out.
  prep_kernel<<<dim3(12288 + 4096), 256, 0, stream>>>(
      query, key_in, value, Xb, Wq, Wk, Wv, Wo, WT);
  gemm_qkv_kernel<<<dim3(kE / 128, kM / 128, 3), 256, 0, stream>>>(
      Xb, WT, bq, bk, bv, Qb, Kb, VTb);
  attn_kernel<<<dim3(kS * kB * kH / 128), 256, 0, stream>>>(Qb, Kb, VTb, AO);
  gemm_out_kernel<<<dim3(kE / 128, kM / 128), 256, 0, stream>>>(
      AO, WT + (size_t)3 * kE * kE, bo, out);
}

// Round 7
// 425.279 us; speedup vs baseline: 1.2191x; 1.0062x over previous
//
#include <hip/hip_runtime.h>
#include <hip/hip_bf16.h>

// MHA: B=2, S=2048, E=2048, H=16, D=128. fp32 in/out, bf16 MFMA internally.
typedef __bf16 bf16;
typedef __bf16 bf16x4 __attribute__((ext_vector_type(4)));
typedef __bf16 bf16x8 __attribute__((ext_vector_type(8)));
typedef float f32x4 __attribute__((ext_vector_type(4)));

constexpr int kE = 2048;
constexpr int kS = 2048;
constexpr int kB = 2;
constexpr int kH = 16;
constexpr int kD = 128;
constexpr int kM = kB * kS;            // 4096 activation rows
constexpr float kQScale = 0.12751743f; // log2(e)/sqrt(D): softmax in exp2 domain

#define MFMA_BF16(A, B, C) __builtin_amdgcn_mfma_f32_16x16x32_bf16((A), (B), (C), 0, 0, 0)

// async global->LDS, 16B/lane. LDS dest must be WAVE-UNIFORM base; HW adds lane*16.
__device__ __forceinline__ void async_ld16(const void* gsrc, void* ldst) {
  __builtin_amdgcn_global_load_lds(
      (__attribute__((address_space(1))) void*)(gsrc),
      (__attribute__((address_space(3))) void*)(ldst), 16, 0, 0);
}

// ---------------------------------------------------------------------------
// Kernel 0 (fused prep): blocks [0,12288) = fp32->bf16 convert of q/k/v;
// blocks [12288,16384) = W -> W^T bf16 for the 4 weight matrices.
__global__ __launch_bounds__(256) void prep_kernel(
    const float* __restrict__ Xq, const float* __restrict__ Xk,
    const float* __restrict__ Xv, bf16* __restrict__ Y,
    const float* __restrict__ Wq, const float* __restrict__ Wk,
    const float* __restrict__ Wv, const float* __restrict__ Wo,
    bf16* __restrict__ WT) {
  __shared__ bf16 tl[64][72];  // wt-branch only ([n][k], +8 pad)
  const int blk = blockIdx.x;
  const int t = threadIdx.x;

  if (blk < 12288) {
    // ---- cvt: 4096 blocks per z, 8 elem/lane
    const int z = blk >> 12;
    const int bx = blk & 4095;
    const float* X = (z == 0) ? Xq : (z == 1) ? Xk : Xv;
    bf16* Yz = Y + (size_t)z * kM * kE;
    size_t i = ((size_t)bx * 256 + t) * 8;
    float4 v0 = *(const float4*)(X + i);
    float4 v1 = *(const float4*)(X + i + 4);
    bf16x8 hv;
    hv[0] = (bf16)v0.x; hv[1] = (bf16)v0.y; hv[2] = (bf16)v0.z; hv[3] = (bf16)v0.w;
    hv[4] = (bf16)v1.x; hv[5] = (bf16)v1.y; hv[6] = (bf16)v1.z; hv[7] = (bf16)v1.w;
    *(bf16x8*)(Yz + i) = hv;
  } else {
    // ---- wt: 1024 blocks per matrix (32x32 tiles of 64x64)
    const int idx = blk - 12288;
    const int z = idx >> 10;
    const int xy = idx & 1023;
    const int n0 = (xy & 31) * 64, k0 = (xy >> 5) * 64;
    const float* W = (z == 0) ? Wq : (z == 1) ? Wk : (z == 2) ? Wv : Wo;
    {
      const int k = t >> 2, nq = (t & 3) * 16;
      const float* src = &W[(size_t)(k0 + k) * kE + n0 + nq];
#pragma unroll
      for (int u = 0; u < 4; ++u) {
        float4 v = *(const float4*)(src + u * 4);
        tl[nq + u * 4 + 0][k] = (bf16)v.x;
        tl[nq + u * 4 + 1][k] = (bf16)v.y;
        tl[nq + u * 4 + 2][k] = (bf16)v.z;
        tl[nq + u * 4 + 3][k] = (bf16)v.w;
      }
    }
    __syncthreads();
    {
      const int n = t >> 2, seg = (t & 3) * 16;
      bf16x8 a = *(const bf16x8*)&tl[n][seg];
      bf16x8 b2 = *(const bf16x8*)&tl[n][seg + 8];
      bf16* dst = &WT[(size_t)(z * kE + n0 + n) * kE + k0 + seg];
      *(bf16x8*)dst = a;
      *(bf16x8*)(dst + 8) = b2;
    }
  }
}

// ---------------------------------------------------------------------------
// Kernel 2: QKV GEMM, 128x128 tile, 2-phase counted-vmcnt dbuf (measured
// 124-127 us = ~830 TF, 92% of this structure's ceiling; frozen).
__global__ __launch_bounds__(256) void gemm_qkv_kernel(
    const bf16* __restrict__ Xb, const bf16* __restrict__ WT,
    const float* __restrict__ bq, const float* __restrict__ bk,
    const float* __restrict__ bv, bf16* __restrict__ Qb,
    bf16* __restrict__ Kb, bf16* __restrict__ VTb) {
  __shared__ alignas(16) bf16 As[2][128 * 64];
  __shared__ alignas(16) bf16 Bs[2][128 * 64];

  const int z = blockIdx.z;
  const bf16* A = Xb + (size_t)z * kM * kE;
  const float* bias = (z == 0) ? bq : (z == 1) ? bk : bv;
  const float oscale = (z == 0) ? kQScale : 1.0f;
  const bf16* Bt = WT + (size_t)z * kE * kE;

  const int n0 = blockIdx.x * 128;
  const int m0 = blockIdx.y * 128;
  const int t = threadIdx.x;
  const int lane = t & 63;
  const int w = t >> 6;
  const int ln = lane & 15;
  const int qd = lane >> 4;
  const int wm = w >> 1, wn = w & 1;

  // stage one 64-wide k-slice of A and B (8 async loads / thread)
  auto stageAB = [&](int buf, int k0) {
#pragma unroll
    for (int i = 0; i < 4; ++i) {
      int c = t + i * 256;
      int row = c >> 3;
      int slot = c & 7;
      int g = slot ^ (row & 7);
      async_ld16(&A[(size_t)(m0 + row) * kE + k0 + g * 8],
                 &As[buf][(size_t)(w * 64 + i * 256) * 8]);
    }
#pragma unroll
    for (int i = 0; i < 4; ++i) {
      int c = t + i * 256;
      int row = c >> 3;
      int slot = c & 7;
      int g = slot ^ (row & 7);
      async_ld16(&Bt[(size_t)(n0 + row) * kE + k0 + g * 8],
                 &Bs[buf][(size_t)(w * 64 + i * 256) * 8]);
    }
  };

  const f32x4 fzero = {0.f, 0.f, 0.f, 0.f};
  f32x4 acc[4][4];
#pragma unroll
  for (int i = 0; i < 4; ++i)
#pragma unroll
    for (int j = 0; j < 4; ++j) acc[i][j] = fzero;

  stageAB(0, 0);  // prologue

#pragma unroll 1
  for (int u = 0; u < 32; ++u) {
    const int cur = u & 1;
    int kn = (u < 31) ? (u + 1) * 64 : 31 * 64;  // last iter: dead re-stage
    stageAB(cur ^ 1, kn);
    // oldest 8 (current tile) landed; 8 (next tile) stay in flight
    asm volatile("s_waitcnt vmcnt(8)" ::: "memory");
    __builtin_amdgcn_s_barrier();
    asm volatile("" ::: "memory");

    __builtin_amdgcn_s_setprio(1);
#pragma unroll
    for (int ks = 0; ks < 2; ++ks) {
      bf16x8 af[4], bfv[4];
#pragma unroll
      for (int i = 0; i < 4; ++i) {
        int row = wm * 64 + i * 16 + ln;
        int slot = (ks * 4 + qd) ^ (ln & 7);
        af[i] = *(const bf16x8*)&As[cur][row * 64 + slot * 8];
      }
#pragma unroll
      for (int j = 0; j < 4; ++j) {
        int row = wn * 64 + j * 16 + ln;
        int slot = (ks * 4 + qd) ^ (ln & 7);
        bfv[j] = *(const bf16x8*)&Bs[cur][row * 64 + slot * 8];
      }
#pragma unroll
      for (int i = 0; i < 4; ++i)
#pragma unroll
        for (int j = 0; j < 4; ++j)
          acc[i][j] = MFMA_BF16(af[i], bfv[j], acc[i][j]);
    }
    __builtin_amdgcn_s_setprio(0);

    // all waves done reading buf `cur` before next iter re-stages it
    asm volatile("s_waitcnt lgkmcnt(0)" ::: "memory");
    __builtin_amdgcn_s_barrier();
    asm volatile("" ::: "memory");
  }

  // epilogue: +bias (+scale for Q). Q/K: coalesced (B,H,S,D). V: direct V^T
  // (B,H,D,S) -- consecutive r = consecutive s for fixed d -> bf16x4 store.
  if (z != 2) {
    bf16* dstbuf = (z == 0) ? Qb : Kb;
#pragma unroll
    for (int i = 0; i < 4; ++i) {
      int mbase = m0 + wm * 64 + i * 16 + qd * 4;
#pragma unroll
      for (int j = 0; j < 4; ++j) {
        int n = n0 + wn * 64 + j * 16 + ln;
        float bn = bias[n];
        int h = n >> 7, d = n & 127;
#pragma unroll
        for (int r = 0; r < 4; ++r) {
          int mm = mbase + r;
          int bb = mm >> 11, ss = mm & (kS - 1);
          dstbuf[((size_t)(bb * kH + h) * kS + ss) * kD + d] =
              (bf16)((acc[i][j][r] + bn) * oscale);
        }
      }
    }
  } else {
#pragma unroll
    for (int i = 0; i < 4; ++i) {
      int mbase = m0 + wm * 64 + i * 16 + qd * 4;
      int bb = mbase >> 11, ss0 = mbase & (kS - 1);
#pragma unroll
      for (int j = 0; j < 4; ++j) {
        int n = n0 + wn * 64 + j * 16 + ln;
        float bn = bias[n];
        int h = n >> 7, d = n & 127;
        bf16x4 v;
#pragma unroll
        for (int r = 0; r < 4; ++r) v[r] = (bf16)(acc[i][j][r] + bn);
        *(bf16x4*)&VTb[((size_t)(bb * kH + h) * kD + d) * kS + ss0] = v;
      }
    }
  }
}

// ---------------------------------------------------------------------------
// Kernel 3: flash attention, QBLK=128 (4 waves x 32 q-rows, 2 m-frags/wave).
// Round-7 change: SWAPPED QK^T -- compute mfma(K, Q) instead of mfma(Q, K).
// A/B fragments have identical per-lane layouts (row=lane&15, k=qd*8+j), so
// the swap is a pure argument flip; C transposes to [key][query]. Each lane
// then holds 4 consecutive KEYS for one query -> P-store becomes 8 x
// ds_write_b64 (was 32 scalar ds_write_u16), the row-sum becomes a scalar
// lsum[m] (2-shuffle reduce), and the PV-side P-reads stay byte-identical.
// Mapping invariant: P[row][k] lives at row*64 + ((k/8)^(row&7))*8 + k%8.
__global__ __launch_bounds__(256) void attn_kernel(
    const bf16* __restrict__ Qb, const bf16* __restrict__ Kb,
    const bf16* __restrict__ VTb, bf16* __restrict__ AO) {
  __shared__ alignas(16) bf16 Kt[2][64 * 128];
  __shared__ alignas(16) bf16 Vt[2][128 * 64];
  __shared__ alignas(16) bf16 Pl[4][32 * 64];

  const int wg = blockIdx.x;
  const int swz = (wg & 7) * 64 + (wg >> 3);   // bijective, 512 % 8 == 0
  const int bh = swz >> 4;                     // 0..31  (= b*16 + h)
  const int q0 = (swz & 15) * 128;
  const int t = threadIdx.x, lane = t & 63, w = t >> 6;
  const int ln = lane & 15, qd = lane >> 4;

  const bf16* Qh = Qb + (size_t)bh * kS * kD;
  const bf16* Kh = Kb + (size_t)bh * kS * kD;
  const bf16* Vh = VTb + (size_t)bh * kD * kS;

  bf16x8 qf[2][4];  // Q frags: query = ln (B-operand col), k = f*32+qd*8+j (d)
#pragma unroll
  for (int m = 0; m < 2; ++m) {
    int qr = q0 + w * 32 + m * 16 + ln;
#pragma unroll
    for (int f = 0; f < 4; ++f)
      qf[m][f] = *(const bf16x8*)&Qh[(size_t)qr * kD + f * 32 + qd * 8];
  }

  auto stage = [&](int buf, int kc) {
#pragma unroll
    for (int i = 0; i < 4; ++i) {
      int c = t + i * 256;
      int row = c >> 4;
      int slot = c & 15;
      int g = slot ^ (row & 15);
      async_ld16(&Kh[(size_t)(kc + row) * kD + g * 8],
                 &Kt[buf][(size_t)(w * 64 + i * 256) * 8]);
    }
#pragma unroll
    for (int i = 0; i < 4; ++i) {
      int c = t + i * 256;
      int row = c >> 3;
      int slot = c & 7;
      int g = slot ^ (row & 7);
      async_ld16(&Vh[(size_t)row * kS + kc + g * 8],
                 &Vt[buf][(size_t)(w * 64 + i * 256) * 8]);
    }
  };

  const f32x4 fzero = {0.f, 0.f, 0.f, 0.f};
  f32x4 o[2][8];
#pragma unroll
  for (int m = 0; m < 2; ++m)
#pragma unroll
    for (int dt = 0; dt < 8; ++dt) o[m][dt] = fzero;
  float lsum[2] = {0.f, 0.f};

  stage(0, 0);  // prologue

#pragma unroll 1
  for (int u = 0; u < 32; ++u) {
    const int cur = u & 1;
    int knext = (u < 31) ? (u + 1) * 64 : 31 * 64;
    stage(cur ^ 1, knext);
    asm volatile("s_waitcnt vmcnt(8)" ::: "memory");
    __builtin_amdgcn_s_barrier();
    asm volatile("" ::: "memory");

    // S^T = K * Q^T : C row = key(qd*4+r), col = query(ln) per 16-tile
    f32x4 s[2][4];
#pragma unroll
    for (int m = 0; m < 2; ++m)
#pragma unroll
      for (int nt = 0; nt < 4; ++nt) s[m][nt] = fzero;
    __builtin_amdgcn_s_setprio(1);
#pragma unroll
    for (int nt = 0; nt < 4; ++nt) {
      int row = nt * 16 + ln;
#pragma unroll
      for (int f = 0; f < 4; ++f) {
        int slot = (f * 4 + qd) ^ ln;  // row&15 == ln
        bf16x8 kfv = *(const bf16x8*)&Kt[cur][row * 128 + slot * 8];
        s[0][nt] = MFMA_BF16(kfv, qf[0][f], s[0][nt]);  // swapped operands
        s[1][nt] = MFMA_BF16(kfv, qf[1][f], s[1][nt]);
      }
    }
    __builtin_amdgcn_s_setprio(0);

    // P = exp2(S^T): lane holds keys nt*16+qd*4+r for query m*16+ln.
    // Scalar lsum accumulate; vectorized b64 P-store (swizzle-consistent
    // with the b128 read: P[row][k] at row*64 + ((k/8)^(row&7))*8 + k%8).
#pragma unroll
    for (int m = 0; m < 2; ++m)
#pragma unroll
      for (int nt = 0; nt < 4; ++nt) {
        bf16x4 pv4;
#pragma unroll
        for (int r = 0; r < 4; ++r) {
          float p = __builtin_amdgcn_exp2f(s[m][nt][r]);
          lsum[m] += p;
          pv4[r] = (bf16)p;
        }
        int slot = (nt * 2 + (qd >> 1)) ^ (ln & 7);
        *(bf16x4*)&Pl[w][(m * 16 + ln) * 64 + slot * 8 + (qd & 1) * 4] = pv4;
      }
    asm volatile("s_waitcnt lgkmcnt(0)" ::: "memory");  // per-wave P handoff

    // O += P * V : A = P (m=query, k=key), B = V (k=key, n=d). Unchanged.
    bf16x8 pf[2][2];
#pragma unroll
    for (int m = 0; m < 2; ++m)
#pragma unroll
      for (int kf = 0; kf < 2; ++kf) {
        int slot = (kf * 4 + qd) ^ (ln & 7);
        pf[m][kf] = *(const bf16x8*)&Pl[w][(m * 16 + ln) * 64 + slot * 8];
      }
    __builtin_amdgcn_s_setprio(1);
#pragma unroll
    for (int dt = 0; dt < 8; ++dt) {
      int row = dt * 16 + ln;
#pragma unroll
      for (int kf = 0; kf < 2; ++kf) {
        int slot = (kf * 4 + qd) ^ (ln & 7);
        bf16x8 vv = *(const bf16x8*)&Vt[cur][row * 64 + slot * 8];
        o[0][dt] = MFMA_BF16(pf[0][kf], vv, o[0][dt]);
        o[1][dt] = MFMA_BF16(pf[1][kf], vv, o[1][dt]);
      }
    }
    __builtin_amdgcn_s_setprio(0);

    asm volatile("s_waitcnt lgkmcnt(0)" ::: "memory");
    __builtin_amdgcn_s_barrier();
    asm volatile("" ::: "memory");
  }

  // epilogue: lsum[m] holds this lane's partial over its 16 keys/tile for
  // query m*16+ln; full row-sum = reduce across the 4 qd groups.
  float inv[2];
#pragma unroll
  for (int m = 0; m < 2; ++m) {
    float l = lsum[m];
    l += __shfl_xor(l, 16);
    l += __shfl_xor(l, 32);
    inv[m] = 1.f / l;
  }
  // o rows are queries m*16+qd*4+r; fetch their inv from lane qd*4+r.
#pragma unroll
  for (int m = 0; m < 2; ++m)
#pragma unroll
    for (int r = 0; r < 4; ++r) {
      float iv = __shfl(inv[m], qd * 4 + r);
      int srow = q0 + w * 32 + m * 16 + qd * 4 + r;
      bf16* dst = AO + (size_t)((bh >> 4) * kS + srow) * kE + (bh & 15) * kD;
#pragma unroll
      for (int dt = 0; dt < 8; ++dt)
        dst[dt * 16 + ln] = (bf16)(o[m][dt][r] * iv);
    }
}

// ---------------------------------------------------------------------------
// Kernel 4: output projection, same 2-phase dbuf skeleton as gemm_qkv.
__global__ __launch_bounds__(256) void gemm_out_kernel(
    const bf16* __restrict__ A, const bf16* __restrict__ Bt,
    const float* __restrict__ bias, float* __restrict__ out) {
  __shared__ alignas(16) bf16 As[2][128 * 64];
  __shared__ alignas(16) bf16 Bs[2][128 * 64];

  const int n0 = blockIdx.x * 128;
  const int m0 = blockIdx.y * 128;
  const int t = threadIdx.x;
  const int lane = t & 63;
  const int w = t >> 6;
  const int ln = lane & 15;
  const int qd = lane >> 4;
  const int wm = w >> 1, wn = w & 1;

  auto stageAB = [&](int buf, int k0) {
#pragma unroll
    for (int i = 0; i < 4; ++i) {
      int c = t + i * 256;
      int row = c >> 3;
      int slot = c & 7;
      int g = slot ^ (row & 7);
      async_ld16(&A[(size_t)(m0 + row) * kE + k0 + g * 8],
                 &As[buf][(size_t)(w * 64 + i * 256) * 8]);
    }
#pragma unroll
    for (int i = 0; i < 4; ++i) {
      int c = t + i * 256;
      int row = c >> 3;
      int slot = c & 7;
      int g = slot ^ (row & 7);
      async_ld16(&Bt[(size_t)(n0 + row) * kE + k0 + g * 8],
                 &Bs[buf][(size_t)(w * 64 + i * 256) * 8]);
    }
  };

  const f32x4 fzero = {0.f, 0.f, 0.f, 0.f};
  f32x4 acc[4][4];
#pragma unroll
  for (int i = 0; i < 4; ++i)
#pragma unroll
    for (int j = 0; j < 4; ++j) acc[i][j] = fzero;

  stageAB(0, 0);  // prologue

#pragma unroll 1
  for (int u = 0; u < 32; ++u) {
    const int cur = u & 1;
    int kn = (u < 31) ? (u + 1) * 64 : 31 * 64;
    stageAB(cur ^ 1, kn);
    asm volatile("s_waitcnt vmcnt(8)" ::: "memory");
    __builtin_amdgcn_s_barrier();
    asm volatile("" ::: "memory");

    __builtin_amdgcn_s_setprio(1);
#pragma unroll
    for (int ks = 0; ks < 2; ++ks) {
      bf16x8 af[4], bfv[4];
#pragma unroll
      for (int i = 0; i < 4; ++i) {
        int row = wm * 64 + i * 16 + ln;
        int slot = (ks * 4 + qd) ^ (ln & 7);
        af[i] = *(const bf16x8*)&As[cur][row * 64 + slot * 8];
      }
#pragma unroll
      for (int j = 0; j < 4; ++j) {
        int row = wn * 64 + j * 16 + ln;
        int slot = (ks * 4 + qd) ^ (ln & 7);
        bfv[j] = *(const bf16x8*)&Bs[cur][row * 64 + slot * 8];
      }
#pragma unroll
      for (int i = 0; i < 4; ++i)
#pragma unroll
        for (int j = 0; j < 4; ++j)
          acc[i][j] = MFMA_BF16(af[i], bfv[j], acc[i][j]);
    }
    __builtin_amdgcn_s_setprio(0);

    asm volatile("s_waitcnt lgkmcnt(0)" ::: "memory");
    __builtin_amdgcn_s_barrier();
    asm volatile("" ::: "memory");
  }

#pragma unroll
  for (int i = 0; i < 4; ++i) {
    int mbase = m0 + wm * 64 + i * 16 + qd * 4;
#pragma unroll
    for (int j = 0; j < 4; ++j) {
      int n = n0 + wn * 64 + j * 16 + ln;
      float bn = bias[n];
#pragma unroll
      for (int r = 0; r < 4; ++r) {
        int mm = mbase + r;
        out[(size_t)mm * kE + n] = acc[i][j][r] + bn;
      }
    }
  }
}

// ---------------------------------------------------------------------------
extern "C" void kernel_launch(void* const* d_in, const int* in_sizes, int n_in,
                              void* d_out, int out_size, void* d_ws,
                              size_t ws_size, hipStream_t stream) {
  const float* query  = (const float*)d_in[0];
  const float* key_in = (const float*)d_in[1];
  const float* value  = (const float*)d_in[2];
  const float* Wq = (const float*)d_in[3];
  const float* bq = (const float*)d_in[4];
  const float* Wk = (const float*)d_in[5];
  const float* bk = (const float*)d_in[6];
  const float* Wv = (const float*)d_in[7];
  const float* bv = (const float*)d_in[8];
  const float* Wo = (const float*)d_in[9];
  const float* bo = (const float*)d_in[10];
  float* out = (float*)d_out;

  // ws layout (bf16): WT[4*E*E] | Q | K | VT | AO (each kM*kE) | Xb[3*kM*kE]
  const size_t szWT  = (size_t)4 * kE * kE;
  const size_t szAct = (size_t)kM * kE;
  const size_t need = (szWT + 7 * szAct) * sizeof(bf16);  // ~151 MB
  if (ws_size < need) return;

  bf16* WT  = (bf16*)d_ws;
  bf16* Qb  = WT + szWT;
  bf16* Kb  = Qb + szAct;
  bf16* VTb = Kb + szAct;
  bf16* AO  = VTb + szAct;
  bf16* Xb  = AO + szAct;

  // 4 dispatches: prep (cvt+wt), qkv (V^T fused), attn, out.
  prep_kernel<<<dim3(12288 + 4096), 256, 0, stream>>>(
      query, key_in, value, Xb, Wq, Wk, Wv, Wo, WT);
  gemm_qkv_kernel<<<dim3(kE / 128, kM / 128, 3), 256, 0, stream>>>(
      Xb, WT, bq, bk, bv, Qb, Kb, VTb);
  attn_kernel<<<dim3(kS * kB * kH / 128), 256, 0, stream>>>(Qb, Kb, VTb, AO);
  gemm_out_kernel<<<dim3(kE / 128, kM / 128), 256, 0, stream>>>(
      AO, WT + (size_t)3 * kE * kE, bo, out);
}